// Round 1
// baseline (8887.096 us; speedup 1.0000x reference)
//
#include <hip/hip_runtime.h>
#include <cstddef>

#define N_NODES 2048
#define BATCH   4
#define FDIM    256
#define HDIM    512
#define NEDGE   65536
#define BN      8192          // BATCH * N_NODES
#define DT      0.25f         // (t1-t0)/n_steps

// ---------------- Laplacian build ----------------

// edge MLP: ew = sigmoid(relu(attr*w1+b1) @ w2 + b2); also unweighted degree count on col
__global__ void edge_ew_deg(const float* __restrict__ attr, const int* __restrict__ eidx,
                            const float* __restrict__ w1, const float* __restrict__ b1,
                            const float* __restrict__ w2, const float* __restrict__ b2,
                            float* __restrict__ ew, float* __restrict__ deg) {
    int e = blockIdx.x * blockDim.x + threadIdx.x;
    if (e >= NEDGE) return;
    float a = attr[e];
    float s = b2[0];
#pragma unroll
    for (int k = 0; k < 32; ++k)
        s += fmaxf(fmaf(a, w1[k], b1[k]), 0.f) * w2[k];
    ew[e] = 1.f / (1.f + expf(-s));
    atomicAdd(&deg[eidx[NEDGE + e]], 1.f);
}

// dis = (deg+1)^-1/2 (self loop adds 1); diagonal of L = 1 - 1/(deg+1)
__global__ void dis_diag(const float* __restrict__ deg, float* __restrict__ dis,
                         float* __restrict__ L) {
    int n = blockIdx.x * blockDim.x + threadIdx.x;
    if (n >= N_NODES) return;
    float d = deg[n] + 1.f;
    dis[n] = rsqrtf(d);
    L[(size_t)n * N_NODES + n] = 1.f - 1.f / d;   // 1 - dis^2 (self-loop weight 1)
}

__global__ void scatter_L(const int* __restrict__ eidx, const float* __restrict__ ew,
                          const float* __restrict__ dis, float* __restrict__ L) {
    int e = blockIdx.x * blockDim.x + threadIdx.x;
    if (e >= NEDGE) return;
    int r = eidx[e], c = eidx[NEDGE + e];
    atomicAdd(&L[(size_t)r * N_NODES + c], -dis[r] * ew[e] * dis[c]);
}

// ctxproj[b,h] = td_b1[h] + sum_k ctx[b,k] * td_w1[256+k, h]  (stage-invariant)
__global__ void ctxproj_kernel(const float* __restrict__ ctx, const float* __restrict__ w1,
                               const float* __restrict__ b1, float* __restrict__ out) {
    int b = blockIdx.x, h = threadIdx.x;
    const float* W = w1 + (size_t)FDIM * HDIM + h;   // rows 256..511
    const float* c = ctx + b * FDIM;
    float s = b1[h];
#pragma unroll 4
    for (int k = 0; k < FDIM; ++k)
        s = fmaf(c[k], W[(size_t)k * HDIM], s);
    out[b * HDIM + h] = s;
}

// ---------------- generic fp32 tiled GEMM ----------------
// C[M,N] = A[M,K] @ B[K,N] (+bias)(+relu). blockIdx.z batches B and C (A shared).
// BIAS_MODE: 0 none, 1 bias[col], 2 bias[(row>>11)*N + col] (per-batch row bias)
template<int BIAS_MODE, int RELU>
__global__ __launch_bounds__(256)
void gemm_f32(const float* __restrict__ A, const float* __restrict__ B,
              const float* __restrict__ bias, float* __restrict__ C,
              int M, int N, int K, long strideB, long strideC) {
    __shared__ float As[16][65];                  // +1 pad: kills 16-way ds_write conflict
    __shared__ __align__(16) float Bs[16][64];
    const float* Bp = B + (size_t)blockIdx.z * strideB;
    float* Cp = C + (size_t)blockIdx.z * strideC;
    int tid = threadIdx.x;
    int tx = tid & 15, ty = tid >> 4;
    int rowBase = blockIdx.y * 64;
    int colBase = blockIdx.x * 64;
    float acc[4][4] = {};
    for (int k0 = 0; k0 < K; k0 += 16) {
#pragma unroll
        for (int i = 0; i < 4; ++i) {             // A tile 64x16 -> As[k][m]
            int idx = tid + i * 256;
            int m = idx >> 4, kk = idx & 15;
            As[kk][m] = A[(size_t)(rowBase + m) * K + k0 + kk];
        }
#pragma unroll
        for (int i = 0; i < 4; ++i) {             // B tile 16x64
            int idx = tid + i * 256;
            int kk = idx >> 6, n = idx & 63;
            Bs[kk][n] = Bp[(size_t)(k0 + kk) * N + colBase + n];
        }
        __syncthreads();
#pragma unroll
        for (int kk = 0; kk < 16; ++kk) {
            float a0 = As[kk][ty * 4 + 0], a1 = As[kk][ty * 4 + 1];
            float a2 = As[kk][ty * 4 + 2], a3 = As[kk][ty * 4 + 3];
            float4 bv = *(const float4*)&Bs[kk][tx * 4];
            acc[0][0] = fmaf(a0, bv.x, acc[0][0]); acc[0][1] = fmaf(a0, bv.y, acc[0][1]);
            acc[0][2] = fmaf(a0, bv.z, acc[0][2]); acc[0][3] = fmaf(a0, bv.w, acc[0][3]);
            acc[1][0] = fmaf(a1, bv.x, acc[1][0]); acc[1][1] = fmaf(a1, bv.y, acc[1][1]);
            acc[1][2] = fmaf(a1, bv.z, acc[1][2]); acc[1][3] = fmaf(a1, bv.w, acc[1][3]);
            acc[2][0] = fmaf(a2, bv.x, acc[2][0]); acc[2][1] = fmaf(a2, bv.y, acc[2][1]);
            acc[2][2] = fmaf(a2, bv.z, acc[2][2]); acc[2][3] = fmaf(a2, bv.w, acc[2][3]);
            acc[3][0] = fmaf(a3, bv.x, acc[3][0]); acc[3][1] = fmaf(a3, bv.y, acc[3][1]);
            acc[3][2] = fmaf(a3, bv.z, acc[3][2]); acc[3][3] = fmaf(a3, bv.w, acc[3][3]);
        }
        __syncthreads();
    }
#pragma unroll
    for (int i = 0; i < 4; ++i) {
        int r = rowBase + ty * 4 + i;
        float* crow = Cp + (size_t)r * N + colBase + tx * 4;
#pragma unroll
        for (int j = 0; j < 4; ++j) {
            float v = acc[i][j];
            if (BIAS_MODE == 1) v += bias[colBase + tx * 4 + j];
            if (BIAS_MODE == 2) v += bias[(r >> 11) * N + colBase + tx * 4 + j];
            if (RELU) v = fmaxf(v, 0.f);
            crow[j] = v;
        }
    }
}

// ---------------- LayerNorm(512) + ReLU, in place ----------------
__global__ __launch_bounds__(256)
void ln_relu_512(float* __restrict__ data, const float* __restrict__ g,
                 const float* __restrict__ b) {
    int row = blockIdx.x;
    float* x = data + (size_t)row * HDIM;
    int t = threadIdx.x;
    float v0 = x[t], v1 = x[t + 256];
    float s = v0 + v1, s2 = v0 * v0 + v1 * v1;
#pragma unroll
    for (int o = 32; o > 0; o >>= 1) { s += __shfl_down(s, o); s2 += __shfl_down(s2, o); }
    __shared__ float red[8];
    int w = t >> 6;
    if ((t & 63) == 0) { red[w] = s; red[4 + w] = s2; }
    __syncthreads();
    s  = red[0] + red[1] + red[2] + red[3];
    s2 = red[4] + red[5] + red[6] + red[7];
    float mu  = s * (1.f / HDIM);
    float var = fmaf(-mu, mu, s2 * (1.f / HDIM));
    float inv = rsqrtf(var + 1e-5f);
    x[t]       = fmaxf(fmaf((v0 - mu) * inv, g[t],       b[t]),       0.f);
    x[t + 256] = fmaxf(fmaf((v1 - mu) * inv, g[t + 256], b[t + 256]), 0.f);
}

// ---------------- dcoef[row] = sigmoid(dot(hdf[row,:], w2) + b2), one wave/row ----------------
__global__ __launch_bounds__(256)
void dcoef_kernel(const float* __restrict__ hdf, const float* __restrict__ w2,
                  const float* __restrict__ b2, float* __restrict__ dcoef) {
    int row = blockIdx.x * 4 + (threadIdx.x >> 6);
    int lane = threadIdx.x & 63;
    float4 h = ((const float4*)(hdf + (size_t)row * FDIM))[lane];
    float4 w = ((const float4*)w2)[lane];
    float s = h.x * w.x + h.y * w.y + h.z * w.z + h.w * w.w;
#pragma unroll
    for (int o = 32; o > 0; o >>= 1) s += __shfl_down(s, o);
    if (lane == 0) dcoef[row] = 1.f / (1.f + expf(-(s + b2[0])));
}

// ks = ks - dcoef[row] * Lh   (row = i/256)
__global__ void finish_k(float* __restrict__ ks, const float* __restrict__ Lh,
                         const float* __restrict__ dc) {
    int i = blockIdx.x * blockDim.x + threadIdx.x;
    ks[i] = ks[i] - dc[i >> 8] * Lh[i];
}

// out = base + sum_i c_i * p_i  (null p skipped)
__global__ void combine5(float* __restrict__ out, const float* __restrict__ base,
                         const float* __restrict__ p0, const float* __restrict__ p1,
                         const float* __restrict__ p2, const float* __restrict__ p3,
                         const float* __restrict__ p4,
                         float c0, float c1, float c2, float c3, float c4) {
    int i = blockIdx.x * blockDim.x + threadIdx.x;
    float v = base[i];
    if (p0) v = fmaf(c0, p0[i], v);
    if (p1) v = fmaf(c1, p1[i], v);
    if (p2) v = fmaf(c2, p2[i], v);
    if (p3) v = fmaf(c3, p3[i], v);
    if (p4) v = fmaf(c4, p4[i], v);
    out[i] = v;
}

extern "C" void kernel_launch(void* const* d_in, const int* in_sizes, int n_in,
                              void* d_out, int out_size, void* d_ws, size_t ws_size,
                              hipStream_t stream) {
    const float* state      = (const float*)d_in[0];
    const float* context    = (const float*)d_in[1];
    const float* edge_attr  = (const float*)d_in[2];
    const int*   edge_index = (const int*)d_in[3];
    const float* ew_w1 = (const float*)d_in[4];
    const float* ew_b1 = (const float*)d_in[5];
    const float* ew_w2 = (const float*)d_in[6];
    const float* ew_b2 = (const float*)d_in[7];
    const float* td_w1 = (const float*)d_in[8];
    const float* td_b1 = (const float*)d_in[9];
    const float* ln1_g = (const float*)d_in[10];
    const float* ln1_b = (const float*)d_in[11];
    const float* td_w2 = (const float*)d_in[12];
    const float* td_b2 = (const float*)d_in[13];
    const float* ln2_g = (const float*)d_in[14];
    const float* ln2_b = (const float*)d_in[15];
    const float* td_w3 = (const float*)d_in[16];
    const float* td_b3 = (const float*)d_in[17];
    const float* df_w1 = (const float*)d_in[18];
    const float* df_b1 = (const float*)d_in[19];
    const float* df_w2 = (const float*)d_in[20];
    const float* df_b2 = (const float*)d_in[21];
    float* out = (float*)d_out;

    float* ws = (float*)d_ws;
    size_t off = 0;
    auto alloc = [&](size_t n) { float* p = ws + off; off += n; return p; };
    float* ew    = alloc(NEDGE);
    float* deg   = alloc(N_NODES);
    float* dis   = alloc(N_NODES);
    float* ctxp  = alloc((size_t)BATCH * HDIM);
    float* dcoef = alloc(BN);
    float* L     = alloc((size_t)N_NODES * N_NODES);
    float* y     = alloc((size_t)BN * FDIM);
    float* yi    = alloc((size_t)BN * FDIM);
    float* h1    = alloc((size_t)BN * HDIM);
    float* h2    = alloc((size_t)BN * HDIM);
    float* hdf   = alloc((size_t)BN * FDIM);   // reused as Lh after dcoef
    float* kb[6];
    for (int s = 0; s < 6; ++s) kb[s] = alloc((size_t)BN * FDIM);

    // ---- Laplacian (once per call) ----
    hipMemsetAsync(deg, 0, N_NODES * sizeof(float), stream);
    hipMemsetAsync(L, 0, (size_t)N_NODES * N_NODES * sizeof(float), stream);
    edge_ew_deg<<<NEDGE / 256, 256, 0, stream>>>(edge_attr, edge_index, ew_w1, ew_b1, ew_w2, ew_b2, ew, deg);
    dis_diag<<<N_NODES / 256, 256, 0, stream>>>(deg, dis, L);
    scatter_L<<<NEDGE / 256, 256, 0, stream>>>(edge_index, ew, dis, L);
    ctxproj_kernel<<<BATCH, HDIM, 0, stream>>>(context, td_w1, td_b1, ctxp);

    // dopri5 A-rows (stages 1..5); stage 6 is dead (b7=0)
    static const double DPA[6][5] = {
        {0, 0, 0, 0, 0},
        {1.0/5, 0, 0, 0, 0},
        {3.0/40, 9.0/40, 0, 0, 0},
        {44.0/45, -56.0/15, 32.0/9, 0, 0},
        {19372.0/6561, -25360.0/2187, 64448.0/6561, -212.0/729, 0},
        {9017.0/3168, -355.0/33, 46732.0/5247, 49.0/176, -5103.0/18656},
    };

    const int NELT = BN * FDIM;              // 2,097,152
    const float* ycur = state;
    for (int step = 0; step < 4; ++step) {
        for (int s = 0; s < 6; ++s) {
            const float* fin;
            if (s == 0) {
                fin = ycur;
            } else {
                const float* p[5] = {nullptr, nullptr, nullptr, nullptr, nullptr};
                float c[5] = {0, 0, 0, 0, 0};
                for (int j = 0; j < s; ++j) { p[j] = kb[j]; c[j] = (float)(DT * DPA[s][j]); }
                combine5<<<NELT / 256, 256, 0, stream>>>(yi, ycur, p[0], p[1], p[2], p[3], p[4],
                                                         c[0], c[1], c[2], c[3], c[4]);
                fin = yi;
            }
            float* ks = kb[s];
            // temporal decoder
            gemm_f32<2, 0><<<dim3(HDIM / 64, BN / 64, 1), 256, 0, stream>>>(
                fin, td_w1, ctxp, h1, BN, HDIM, FDIM, 0, 0);
            ln_relu_512<<<BN, 256, 0, stream>>>(h1, ln1_g, ln1_b);
            gemm_f32<1, 0><<<dim3(HDIM / 64, BN / 64, 1), 256, 0, stream>>>(
                h1, td_w2, td_b2, h2, BN, HDIM, HDIM, 0, 0);
            ln_relu_512<<<BN, 256, 0, stream>>>(h2, ln2_g, ln2_b);
            gemm_f32<1, 0><<<dim3(FDIM / 64, BN / 64, 1), 256, 0, stream>>>(
                h2, td_w3, td_b3, ks, BN, FDIM, HDIM, 0, 0);
            // diffusion coefficient MLP
            gemm_f32<1, 1><<<dim3(FDIM / 64, BN / 64, 1), 256, 0, stream>>>(
                fin, df_w1, df_b1, hdf, BN, FDIM, FDIM, 0, 0);
            dcoef_kernel<<<BN / 4, 256, 0, stream>>>(hdf, df_w2, df_b2, dcoef);
            // diffusion: Lh[b] = L @ yi[b]   (reuses hdf as Lh)
            gemm_f32<0, 0><<<dim3(FDIM / 64, N_NODES / 64, BATCH), 256, 0, stream>>>(
                L, fin, nullptr, hdf, N_NODES, FDIM, N_NODES,
                (long)N_NODES * FDIM, (long)N_NODES * FDIM);
            finish_k<<<NELT / 256, 256, 0, stream>>>(ks, hdf, dcoef);
        }
        float* dst = (step == 3) ? out : y;
        combine5<<<NELT / 256, 256, 0, stream>>>(dst, ycur,
            kb[0], kb[2], kb[3], kb[4], kb[5],
            (float)(DT * 35.0 / 384), (float)(DT * 500.0 / 1113), (float)(DT * 125.0 / 192),
            (float)(DT * -2187.0 / 6784), (float)(DT * 11.0 / 84));
        ycur = y;
    }
    (void)in_sizes; (void)n_in; (void)out_size; (void)ws_size;
}

// Round 4
// 2788.619 us; speedup vs baseline: 3.1869x; 3.1869x over previous
//
#include <hip/hip_runtime.h>
#include <cstddef>
#include <cstdint>

#define N_NODES 2048
#define BATCH   4
#define FDIM    256
#define HDIM    512
#define NEDGE   65536
#define BN_     8192          // BATCH * N_NODES
#define DT      0.25f

typedef __attribute__((ext_vector_type(8))) __bf16 bf16x8;
typedef __attribute__((ext_vector_type(4))) float f32x4;

__device__ __forceinline__ ushort f2bf(float f) {
    union { float f; unsigned u; } v; v.f = f;
    return (ushort)((v.u + 0x7FFF + ((v.u >> 16) & 1)) >> 16);   // RNE
}

__device__ __forceinline__ void gload16(const void* g, void* l) {
    __builtin_amdgcn_global_load_lds((const __attribute__((address_space(1))) void*)g,
                                     (__attribute__((address_space(3))) void*)l, 16, 0, 0);
}

// ---------------- Laplacian build ----------------
__global__ void edge_ew_deg(const float* __restrict__ attr, const int* __restrict__ eidx,
                            const float* __restrict__ w1, const float* __restrict__ b1,
                            const float* __restrict__ w2, const float* __restrict__ b2,
                            float* __restrict__ ew, float* __restrict__ deg) {
    int e = blockIdx.x * blockDim.x + threadIdx.x;
    if (e >= NEDGE) return;
    float a = attr[e];
    float s = b2[0];
#pragma unroll
    for (int k = 0; k < 32; ++k)
        s += fmaxf(fmaf(a, w1[k], b1[k]), 0.f) * w2[k];
    ew[e] = 1.f / (1.f + expf(-s));
    atomicAdd(&deg[eidx[NEDGE + e]], 1.f);
}

__global__ void dis_diag(const float* __restrict__ deg, float* __restrict__ dis,
                         float* __restrict__ L) {
    int n = blockIdx.x * blockDim.x + threadIdx.x;
    if (n >= N_NODES) return;
    float d = deg[n] + 1.f;
    dis[n] = rsqrtf(d);
    L[(size_t)n * N_NODES + n] = 1.f - 1.f / d;
}

__global__ void scatter_L(const int* __restrict__ eidx, const float* __restrict__ ew,
                          const float* __restrict__ dis, float* __restrict__ L) {
    int e = blockIdx.x * blockDim.x + threadIdx.x;
    if (e >= NEDGE) return;
    int r = eidx[e], c = eidx[NEDGE + e];
    atomicAdd(&L[(size_t)r * N_NODES + c], -dis[r] * ew[e] * dis[c]);
}

__global__ void ctxproj_kernel(const float* __restrict__ ctx, const float* __restrict__ w1,
                               const float* __restrict__ b1, float* __restrict__ out) {
    int b = blockIdx.x, h = threadIdx.x;
    const float* W = w1 + (size_t)FDIM * HDIM + h;
    const float* c = ctx + b * FDIM;
    float s = b1[h];
#pragma unroll 4
    for (int k = 0; k < FDIM; ++k)
        s = fmaf(c[k], W[(size_t)k * HDIM], s);
    out[b * HDIM + h] = s;
}

// ---------------- one-time converts ----------------
// out[c*R + r] = bf16(in[r*inStride + c]);  grid (R/64, C/64), 256 thr
__global__ __launch_bounds__(256)
void transpose_cvt(const float* __restrict__ in, int inStride, ushort* __restrict__ out,
                   int R, int C) {
    __shared__ float tile[64][65];
    int r0 = blockIdx.x * 64, c0 = blockIdx.y * 64;
    int t = threadIdx.x, tr = t >> 4, tc = t & 15;
#pragma unroll
    for (int i = 0; i < 4; ++i) {
        float4 v = *(const float4*)&in[(size_t)(r0 + tr + i * 16) * inStride + c0 + tc * 4];
        tile[tr + i * 16][tc * 4 + 0] = v.x; tile[tr + i * 16][tc * 4 + 1] = v.y;
        tile[tr + i * 16][tc * 4 + 2] = v.z; tile[tr + i * 16][tc * 4 + 3] = v.w;
    }
    __syncthreads();
#pragma unroll
    for (int i = 0; i < 4; ++i) {
        int c = tr + i * 16;
        ushort4 o = make_ushort4(f2bf(tile[tc * 4 + 0][c]), f2bf(tile[tc * 4 + 1][c]),
                                 f2bf(tile[tc * 4 + 2][c]), f2bf(tile[tc * 4 + 3][c]));
        *(ushort4*)&out[(size_t)(c0 + c) * R + r0 + tc * 4] = o;
    }
}

__global__ void cvt_bf16(const float* __restrict__ in, ushort* __restrict__ out) {
    int i = blockIdx.x * blockDim.x + threadIdx.x;     // float4 index
    float4 v = ((const float4*)in)[i];
    ((ushort4*)out)[i] = make_ushort4(f2bf(v.x), f2bf(v.y), f2bf(v.z), f2bf(v.w));
}

// bf16 transpose per batch: in [2048][256] -> out [256][2048]; grid (32, 4, BATCH)
__global__ __launch_bounds__(256)
void transpose_bf(const ushort* __restrict__ in, ushort* __restrict__ out) {
    __shared__ ushort tile[64][68];
    int r0 = blockIdx.x * 64, c0 = blockIdx.y * 64;
    const ushort* ip = in + (size_t)blockIdx.z * N_NODES * FDIM;
    ushort* op = out + (size_t)blockIdx.z * N_NODES * FDIM;
    int t = threadIdx.x, tr = t >> 4, tc = t & 15;
#pragma unroll
    for (int i = 0; i < 4; ++i) {
        ushort4 v = *(const ushort4*)&ip[(size_t)(r0 + tr + i * 16) * FDIM + c0 + tc * 4];
        tile[tr + i * 16][tc * 4 + 0] = v.x; tile[tr + i * 16][tc * 4 + 1] = v.y;
        tile[tr + i * 16][tc * 4 + 2] = v.z; tile[tr + i * 16][tc * 4 + 3] = v.w;
    }
    __syncthreads();
#pragma unroll
    for (int i = 0; i < 4; ++i) {
        int c = tr + i * 16;
        ushort4 o = make_ushort4(tile[tc * 4 + 0][c], tile[tc * 4 + 1][c],
                                 tile[tc * 4 + 2][c], tile[tc * 4 + 3][c]);
        *(ushort4*)&op[(size_t)(c0 + c) * N_NODES + r0 + tc * 4] = o;
    }
}

// ---------------- bf16 MFMA GEMM: C[M,N] = A[M,K] @ BT[N,K]^T ----------------
// 128 x BN tile, BK=64, 4 waves (2x2), wave tile 64 x BN/2.
// global_load_lds staging with XOR-swizzled *global source* (LDS stays linear),
// swizzled ds_read_b128 fragment loads (2-way max bank alias = free).
// BIAS_MODE: 0 none, 1 bias[col], 2 bias[(row>>11)*N + col]
template<int BN, int BIAS_MODE, int RELU>
__global__ __launch_bounds__(256)
void gemm_bt(const ushort* __restrict__ A, const ushort* __restrict__ BT,
             const float* __restrict__ bias, float* __restrict__ C,
             int N, int K, long sA, long sB, long sC) {
    constexpr int NR = BN / 32;            // b-frags per wave
    constexpr int BC = (BN * 8) / 256;     // B staging calls per wave
    __shared__ ushort As[128 * 64];
    __shared__ ushort Bs[BN * 64];
    const ushort* Ag = A + (size_t)blockIdx.z * sA;
    const ushort* Bg = BT + (size_t)blockIdx.z * sB;
    float* Cg = C + (size_t)blockIdx.z * sC;
    const int tid = threadIdx.x;
    const int lane = tid & 63, wid = tid >> 6;
    const int wm = wid >> 1, wn = wid & 1;
    const int r15 = lane & 15, g = lane >> 4;
    const int rowBase = blockIdx.y * 128, colBase = blockIdx.x * BN;

    f32x4 acc[4][NR];
#pragma unroll
    for (int m = 0; m < 4; ++m)
#pragma unroll
        for (int n = 0; n < NR; ++n) acc[m][n] = (f32x4){0.f, 0.f, 0.f, 0.f};

    for (int k0 = 0; k0 < K; k0 += 64) {
#pragma unroll
        for (int c = 0; c < 4; ++c) {                  // A tile: 1024 16B chunks
            int ci = wid * 256 + c * 64 + lane;
            int row = ci >> 3, ch = ci & 7;
            gload16(Ag + (size_t)(rowBase + row) * K + k0 + ((ch ^ (row & 7)) << 3),
                    &As[(wid * 256 + c * 64) * 8]);
        }
#pragma unroll
        for (int c = 0; c < BC; ++c) {                 // B tile: BN*8 chunks
            int ci = wid * (BC * 64) + c * 64 + lane;
            int row = ci >> 3, ch = ci & 7;
            gload16(Bg + (size_t)(colBase + row) * K + k0 + ((ch ^ (row & 7)) << 3),
                    &Bs[(wid * (BC * 64) + c * 64) * 8]);
        }
        __syncthreads();                               // drains vmcnt before barrier
#pragma unroll
        for (int kk = 0; kk < 2; ++kk) {
            bf16x8 af[4], bfr[NR];
#pragma unroll
            for (int m = 0; m < 4; ++m) {
                int lr = wm * 64 + m * 16 + r15;
                int off = lr * 128 + ((kk * 64 + g * 16) ^ ((lr & 7) << 4));
                af[m] = *(const bf16x8*)((const char*)As + off);
            }
#pragma unroll
            for (int n = 0; n < NR; ++n) {
                int br = wn * (BN / 2) + n * 16 + r15;
                int off = br * 128 + ((kk * 64 + g * 16) ^ ((br & 7) << 4));
                bfr[n] = *(const bf16x8*)((const char*)Bs + off);
            }
#pragma unroll
            for (int m = 0; m < 4; ++m)
#pragma unroll
                for (int n = 0; n < NR; ++n)
                    acc[m][n] = __builtin_amdgcn_mfma_f32_16x16x32_bf16(
                        af[m], bfr[n], acc[m][n], 0, 0, 0);
        }
        __syncthreads();
    }
#pragma unroll
    for (int m = 0; m < 4; ++m) {
        int row = rowBase + wm * 64 + m * 16 + g * 4;
#pragma unroll
        for (int n = 0; n < NR; ++n) {
            int col = colBase + wn * (BN / 2) + n * 16 + r15;
            float bv = 0.f;
            if (BIAS_MODE == 1) bv = bias[col];
            if (BIAS_MODE == 2) bv = bias[(row >> 11) * N + col];
#pragma unroll
            for (int r = 0; r < 4; ++r) {
                float v = acc[m][n][r] + bv;
                if (RELU) v = fmaxf(v, 0.f);
                Cg[(size_t)(row + r) * N + col] = v;
            }
        }
    }
}

// ---------------- LayerNorm(512) + ReLU: fp32 in -> bf16 out ----------------
__global__ __launch_bounds__(256)
void ln_relu_512(const float* __restrict__ in, ushort* __restrict__ outb,
                 const float* __restrict__ g, const float* __restrict__ b) {
    int row = blockIdx.x;
    const float* x = in + (size_t)row * HDIM;
    int t = threadIdx.x;
    float v0 = x[t], v1 = x[t + 256];
    float s = v0 + v1, s2 = v0 * v0 + v1 * v1;
#pragma unroll
    for (int o = 32; o > 0; o >>= 1) { s += __shfl_down(s, o); s2 += __shfl_down(s2, o); }
    __shared__ float red[8];
    int w = t >> 6;
    if ((t & 63) == 0) { red[w] = s; red[4 + w] = s2; }
    __syncthreads();
    s  = red[0] + red[1] + red[2] + red[3];
    s2 = red[4] + red[5] + red[6] + red[7];
    float mu  = s * (1.f / HDIM);
    float var = fmaf(-mu, mu, s2 * (1.f / HDIM));
    float inv = rsqrtf(var + 1e-5f);
    ushort* o = outb + (size_t)row * HDIM;
    o[t]       = f2bf(fmaxf(fmaf((v0 - mu) * inv, g[t],       b[t]),       0.f));
    o[t + 256] = f2bf(fmaxf(fmaf((v1 - mu) * inv, g[t + 256], b[t + 256]), 0.f));
}

// ---------------- dcoef[row] = sigmoid(dot(hdf[row,:], w2) + b2) ----------------
__global__ __launch_bounds__(256)
void dcoef_kernel(const float* __restrict__ hdf, const float* __restrict__ w2,
                  const float* __restrict__ b2, float* __restrict__ dcoef) {
    int row = blockIdx.x * 4 + (threadIdx.x >> 6);
    int lane = threadIdx.x & 63;
    float4 h = ((const float4*)(hdf + (size_t)row * FDIM))[lane];
    float4 w = ((const float4*)w2)[lane];
    float s = h.x * w.x + h.y * w.y + h.z * w.z + h.w * w.w;
#pragma unroll
    for (int o = 32; o > 0; o >>= 1) s += __shfl_down(s, o);
    if (lane == 0) dcoef[row] = 1.f / (1.f + expf(-(s + b2[0])));
}

// ks -= dcoef[row] * Lh (float4 granularity; 64 float4 per 256-col row)
__global__ void finish_k(float* __restrict__ ks, const float* __restrict__ Lh,
                         const float* __restrict__ dc) {
    int i = blockIdx.x * blockDim.x + threadIdx.x;
    float d = dc[i >> 6];
    float4 a = ((const float4*)ks)[i];
    float4 l = ((const float4*)Lh)[i];
    a.x = fmaf(-d, l.x, a.x); a.y = fmaf(-d, l.y, a.y);
    a.z = fmaf(-d, l.z, a.z); a.w = fmaf(-d, l.w, a.w);
    ((float4*)ks)[i] = a;
}

// out_bf16 = bf16(base + sum c_i p_i)   (float4 granularity)
__global__ void combine_bf16(ushort* __restrict__ out, const float* __restrict__ base,
                             const float* p0, const float* p1, const float* p2,
                             const float* p3, const float* p4,
                             float c0, float c1, float c2, float c3, float c4) {
    int i = blockIdx.x * blockDim.x + threadIdx.x;
    float4 v = ((const float4*)base)[i];
    if (p0) { float4 q = ((const float4*)p0)[i]; v.x = fmaf(c0,q.x,v.x); v.y = fmaf(c0,q.y,v.y); v.z = fmaf(c0,q.z,v.z); v.w = fmaf(c0,q.w,v.w); }
    if (p1) { float4 q = ((const float4*)p1)[i]; v.x = fmaf(c1,q.x,v.x); v.y = fmaf(c1,q.y,v.y); v.z = fmaf(c1,q.z,v.z); v.w = fmaf(c1,q.w,v.w); }
    if (p2) { float4 q = ((const float4*)p2)[i]; v.x = fmaf(c2,q.x,v.x); v.y = fmaf(c2,q.y,v.y); v.z = fmaf(c2,q.z,v.z); v.w = fmaf(c2,q.w,v.w); }
    if (p3) { float4 q = ((const float4*)p3)[i]; v.x = fmaf(c3,q.x,v.x); v.y = fmaf(c3,q.y,v.y); v.z = fmaf(c3,q.z,v.z); v.w = fmaf(c3,q.w,v.w); }
    if (p4) { float4 q = ((const float4*)p4)[i]; v.x = fmaf(c4,q.x,v.x); v.y = fmaf(c4,q.y,v.y); v.z = fmaf(c4,q.z,v.z); v.w = fmaf(c4,q.w,v.w); }
    ((ushort4*)out)[i] = make_ushort4(f2bf(v.x), f2bf(v.y), f2bf(v.z), f2bf(v.w));
}

__global__ void combine_f32(float* __restrict__ out, const float* __restrict__ base,
                            const float* p0, const float* p1, const float* p2,
                            const float* p3, const float* p4,
                            float c0, float c1, float c2, float c3, float c4) {
    int i = blockIdx.x * blockDim.x + threadIdx.x;
    float4 v = ((const float4*)base)[i];
    if (p0) { float4 q = ((const float4*)p0)[i]; v.x = fmaf(c0,q.x,v.x); v.y = fmaf(c0,q.y,v.y); v.z = fmaf(c0,q.z,v.z); v.w = fmaf(c0,q.w,v.w); }
    if (p1) { float4 q = ((const float4*)p1)[i]; v.x = fmaf(c1,q.x,v.x); v.y = fmaf(c1,q.y,v.y); v.z = fmaf(c1,q.z,v.z); v.w = fmaf(c1,q.w,v.w); }
    if (p2) { float4 q = ((const float4*)p2)[i]; v.x = fmaf(c2,q.x,v.x); v.y = fmaf(c2,q.y,v.y); v.z = fmaf(c2,q.z,v.z); v.w = fmaf(c2,q.w,v.w); }
    if (p3) { float4 q = ((const float4*)p3)[i]; v.x = fmaf(c3,q.x,v.x); v.y = fmaf(c3,q.y,v.y); v.z = fmaf(c3,q.z,v.z); v.w = fmaf(c3,q.w,v.w); }
    if (p4) { float4 q = ((const float4*)p4)[i]; v.x = fmaf(c4,q.x,v.x); v.y = fmaf(c4,q.y,v.y); v.z = fmaf(c4,q.z,v.z); v.w = fmaf(c4,q.w,v.w); }
    ((float4*)out)[i] = v;
}

extern "C" void kernel_launch(void* const* d_in, const int* in_sizes, int n_in,
                              void* d_out, int out_size, void* d_ws, size_t ws_size,
                              hipStream_t stream) {
    const float* state      = (const float*)d_in[0];
    const float* context    = (const float*)d_in[1];
    const float* edge_attr  = (const float*)d_in[2];
    const int*   edge_index = (const int*)d_in[3];
    const float* ew_w1 = (const float*)d_in[4];
    const float* ew_b1 = (const float*)d_in[5];
    const float* ew_w2 = (const float*)d_in[6];
    const float* ew_b2 = (const float*)d_in[7];
    const float* td_w1 = (const float*)d_in[8];
    const float* td_b1 = (const float*)d_in[9];
    const float* ln1_g = (const float*)d_in[10];
    const float* ln1_b = (const float*)d_in[11];
    const float* td_w2 = (const float*)d_in[12];
    const float* td_b2 = (const float*)d_in[13];
    const float* ln2_g = (const float*)d_in[14];
    const float* ln2_b = (const float*)d_in[15];
    const float* td_w3 = (const float*)d_in[16];
    const float* td_b3 = (const float*)d_in[17];
    const float* df_w1 = (const float*)d_in[18];
    const float* df_b1 = (const float*)d_in[19];
    const float* df_w2 = (const float*)d_in[20];
    const float* df_b2 = (const float*)d_in[21];
    float* out = (float*)d_out;

    float* ws = (float*)d_ws;
    size_t off = 0;
    auto alloc = [&](size_t nfloats) { float* p = ws + off; off += nfloats; return p; };
    float*  ew    = alloc(NEDGE);
    float*  deg   = alloc(N_NODES);
    float*  dis   = alloc(N_NODES);
    float*  ctxp  = alloc((size_t)BATCH * HDIM);
    float*  dcoef = alloc(BN_);
    float*  L     = alloc((size_t)N_NODES * N_NODES);                 // 16 MB
    ushort* Lbf   = (ushort*)alloc((size_t)N_NODES * N_NODES / 2);    // 8 MB
    float*  y     = alloc((size_t)BN_ * FDIM);                        // 8 MB
    ushort* yi    = (ushort*)alloc((size_t)BN_ * FDIM / 2);           // 4 MB
    ushort* yiT   = (ushort*)alloc((size_t)BN_ * FDIM / 2);           // 4 MB
    float*  h     = alloc((size_t)BN_ * HDIM);                        // 16 MB
    ushort* hb    = (ushort*)alloc((size_t)BN_ * HDIM / 2);           // 8 MB
    float*  hdf   = alloc((size_t)BN_ * FDIM);                        // 8 MB (G4 out, then Lh)
    ushort* w1T   = (ushort*)alloc((size_t)HDIM * FDIM / 2);
    ushort* w2T   = (ushort*)alloc((size_t)HDIM * HDIM / 2);
    ushort* w3T   = (ushort*)alloc((size_t)FDIM * HDIM / 2);
    ushort* dfwT  = (ushort*)alloc((size_t)FDIM * FDIM / 2);
    float* kb[6];
    for (int s = 0; s < 6; ++s) kb[s] = alloc((size_t)BN_ * FDIM);    // 48 MB

    // ---- Laplacian + weight prep (once per call) ----
    hipMemsetAsync(deg, 0, N_NODES * sizeof(float), stream);
    hipMemsetAsync(L, 0, (size_t)N_NODES * N_NODES * sizeof(float), stream);
    edge_ew_deg<<<NEDGE / 256, 256, 0, stream>>>(edge_attr, edge_index, ew_w1, ew_b1, ew_w2, ew_b2, ew, deg);
    dis_diag<<<N_NODES / 256, 256, 0, stream>>>(deg, dis, L);
    scatter_L<<<NEDGE / 256, 256, 0, stream>>>(edge_index, ew, dis, L);
    cvt_bf16<<<(N_NODES * N_NODES / 4) / 256, 256, 0, stream>>>(L, Lbf);
    ctxproj_kernel<<<BATCH, HDIM, 0, stream>>>(context, td_w1, td_b1, ctxp);
    transpose_cvt<<<dim3(FDIM / 64, HDIM / 64), 256, 0, stream>>>(td_w1, HDIM, w1T, FDIM, HDIM);
    transpose_cvt<<<dim3(HDIM / 64, HDIM / 64), 256, 0, stream>>>(td_w2, HDIM, w2T, HDIM, HDIM);
    transpose_cvt<<<dim3(HDIM / 64, FDIM / 64), 256, 0, stream>>>(td_w3, FDIM, w3T, HDIM, FDIM);
    transpose_cvt<<<dim3(FDIM / 64, FDIM / 64), 256, 0, stream>>>(df_w1, FDIM, dfwT, FDIM, FDIM);

    static const double DPA[6][5] = {
        {0, 0, 0, 0, 0},
        {1.0/5, 0, 0, 0, 0},
        {3.0/40, 9.0/40, 0, 0, 0},
        {44.0/45, -56.0/15, 32.0/9, 0, 0},
        {19372.0/6561, -25360.0/2187, 64448.0/6561, -212.0/729, 0},
        {9017.0/3168, -355.0/33, 46732.0/5247, 49.0/176, -5103.0/18656},
    };

    const int NV4 = BN_ * FDIM / 4;   // float4 count = 524288
    const float* ycur = state;
    for (int step = 0; step < 4; ++step) {
        for (int s = 0; s < 6; ++s) {
            const float* p[5] = {nullptr, nullptr, nullptr, nullptr, nullptr};
            float c[5] = {0, 0, 0, 0, 0};
            for (int j = 0; j < s; ++j) { p[j] = kb[j]; c[j] = (float)(DT * DPA[s][j]); }
            combine_bf16<<<NV4 / 256, 256, 0, stream>>>(yi, ycur, p[0], p[1], p[2], p[3], p[4],
                                                        c[0], c[1], c[2], c[3], c[4]);
            transpose_bf<<<dim3(N_NODES / 64, FDIM / 64, BATCH), 256, 0, stream>>>(yi, yiT);
            float* ks = kb[s];
            // temporal decoder
            gemm_bt<128, 2, 0><<<dim3(HDIM / 128, BN_ / 128, 1), 256, 0, stream>>>(
                yi, w1T, ctxp, h, HDIM, FDIM, 0, 0, 0);
            ln_relu_512<<<BN_, 256, 0, stream>>>(h, hb, ln1_g, ln1_b);
            gemm_bt<128, 1, 0><<<dim3(HDIM / 128, BN_ / 128, 1), 256, 0, stream>>>(
                hb, w2T, td_b2, h, HDIM, HDIM, 0, 0, 0);
            ln_relu_512<<<BN_, 256, 0, stream>>>(h, hb, ln2_g, ln2_b);
            gemm_bt<64, 1, 0><<<dim3(FDIM / 64, BN_ / 128, 1), 256, 0, stream>>>(
                hb, w3T, td_b3, ks, FDIM, HDIM, 0, 0, 0);
            // diffusion coefficient MLP
            gemm_bt<64, 1, 1><<<dim3(FDIM / 64, BN_ / 128, 1), 256, 0, stream>>>(
                yi, dfwT, df_b1, hdf, FDIM, FDIM, 0, 0, 0);
            dcoef_kernel<<<BN_ / 4, 256, 0, stream>>>(hdf, df_w2, df_b2, dcoef);
            // diffusion: Lh[b] = L @ yi[b]  (A = Lbf shared, BT = yiT per batch)
            gemm_bt<64, 0, 0><<<dim3(FDIM / 64, N_NODES / 128, BATCH), 256, 0, stream>>>(
                Lbf, yiT, nullptr, hdf, FDIM, N_NODES,
                0, (long)N_NODES * FDIM, (long)N_NODES * FDIM);
            finish_k<<<NV4 / 256, 256, 0, stream>>>(ks, hdf, dcoef);
        }
        float* dst = (step == 3) ? out : y;
        combine_f32<<<NV4 / 256, 256, 0, stream>>>(dst, ycur,
            kb[0], kb[2], kb[3], kb[4], kb[5],
            (float)(DT * 35.0 / 384), (float)(DT * 500.0 / 1113), (float)(DT * 125.0 / 192),
            (float)(DT * -2187.0 / 6784), (float)(DT * 11.0 / 84));
        ycur = y;
    }
    (void)in_sizes; (void)n_in; (void)out_size; (void)ws_size;
}

// Round 6
// 2192.655 us; speedup vs baseline: 4.0531x; 1.2718x over previous
//
#include <hip/hip_runtime.h>
#include <cstddef>
#include <cstdint>

#define N_NODES 2048
#define BATCH   4
#define FDIM    256
#define HDIM    512
#define NEDGE   65536
#define BN_     8192
#define DT      0.25f

typedef __attribute__((ext_vector_type(8))) __bf16 bf16x8;
typedef __attribute__((ext_vector_type(4))) float f32x4;

__device__ __forceinline__ ushort f2bf(float f) {
    union { float f; unsigned u; } v; v.f = f;
    return (ushort)((v.u + 0x7FFF + ((v.u >> 16) & 1)) >> 16);   // RNE
}
__device__ __forceinline__ float bf2f(ushort u) {
    union { float f; unsigned u; } v; v.u = ((unsigned)u) << 16; return v.f;
}
__device__ __forceinline__ void gload16(const void* g, void* l) {
    __builtin_amdgcn_global_load_lds((const __attribute__((address_space(1))) void*)g,
                                     (__attribute__((address_space(3))) void*)l, 16, 0, 0);
}

// ---------------- Laplacian build ----------------
__global__ void edge_ew_deg(const float* __restrict__ attr, const int* __restrict__ eidx,
                            const float* __restrict__ w1, const float* __restrict__ b1,
                            const float* __restrict__ w2, const float* __restrict__ b2,
                            float* __restrict__ ew, float* __restrict__ deg) {
    int e = blockIdx.x * blockDim.x + threadIdx.x;
    if (e >= NEDGE) return;
    float a = attr[e];
    float s = b2[0];
#pragma unroll
    for (int k = 0; k < 32; ++k)
        s += fmaxf(fmaf(a, w1[k], b1[k]), 0.f) * w2[k];
    ew[e] = 1.f / (1.f + expf(-s));
    atomicAdd(&deg[eidx[NEDGE + e]], 1.f);
}

__global__ void dis_diag(const float* __restrict__ deg, float* __restrict__ dis,
                         float* __restrict__ L) {
    int n = blockIdx.x * blockDim.x + threadIdx.x;
    if (n >= N_NODES) return;
    float d = deg[n] + 1.f;
    dis[n] = rsqrtf(d);
    L[(size_t)n * N_NODES + n] = 1.f - 1.f / d;
}

__global__ void scatter_L(const int* __restrict__ eidx, const float* __restrict__ ew,
                          const float* __restrict__ dis, float* __restrict__ L) {
    int e = blockIdx.x * blockDim.x + threadIdx.x;
    if (e >= NEDGE) return;
    int r = eidx[e], c = eidx[NEDGE + e];
    atomicAdd(&L[(size_t)r * N_NODES + c], -dis[r] * ew[e] * dis[c]);
}

__global__ void ctxproj_kernel(const float* __restrict__ ctx, const float* __restrict__ w1,
                               const float* __restrict__ b1, float* __restrict__ out) {
    int b = blockIdx.x, h = threadIdx.x;
    const float* W = w1 + (size_t)FDIM * HDIM + h;
    const float* c = ctx + b * FDIM;
    float s = b1[h];
#pragma unroll 4
    for (int k = 0; k < FDIM; ++k)
        s = fmaf(c[k], W[(size_t)k * HDIM], s);
    out[b * HDIM + h] = s;
}

// out[c*R + r] = bf16(in[r*inStride + c]);  grid (R/64, C/64)
__global__ __launch_bounds__(256)
void transpose_cvt(const float* __restrict__ in, int inStride, ushort* __restrict__ out,
                   int R, int C) {
    __shared__ float tile[64][65];
    int r0 = blockIdx.x * 64, c0 = blockIdx.y * 64;
    int t = threadIdx.x, tr = t >> 4, tc = t & 15;
#pragma unroll
    for (int i = 0; i < 4; ++i) {
        float4 v = *(const float4*)&in[(size_t)(r0 + tr + i * 16) * inStride + c0 + tc * 4];
        tile[tr + i * 16][tc * 4 + 0] = v.x; tile[tr + i * 16][tc * 4 + 1] = v.y;
        tile[tr + i * 16][tc * 4 + 2] = v.z; tile[tr + i * 16][tc * 4 + 3] = v.w;
    }
    __syncthreads();
#pragma unroll
    for (int i = 0; i < 4; ++i) {
        int c = tr + i * 16;
        ushort4 o = make_ushort4(f2bf(tile[tc * 4 + 0][c]), f2bf(tile[tc * 4 + 1][c]),
                                 f2bf(tile[tc * 4 + 2][c]), f2bf(tile[tc * 4 + 3][c]));
        *(ushort4*)&out[(size_t)(c0 + c) * R + r0 + tc * 4] = o;
    }
}

__global__ void cvt_bf16(const float* __restrict__ in, ushort* __restrict__ out) {
    int i = blockIdx.x * blockDim.x + threadIdx.x;
    float4 v = ((const float4*)in)[i];
    ((ushort4*)out)[i] = make_ushort4(f2bf(v.x), f2bf(v.y), f2bf(v.z), f2bf(v.w));
}

// ---------------- combine + dual-layout write: yi (row-major) + yiT (transposed) ----
// grid (N_NODES/64, FDIM/64, BATCH), 256 thr
__global__ __launch_bounds__(256)
void combine_yi(const float* __restrict__ base,
                const float* p0, const float* p1, const float* p2,
                const float* p3, const float* p4,
                float c0, float c1, float c2, float c3, float c4,
                ushort* __restrict__ yi, ushort* __restrict__ yiT) {
    __shared__ ushort tile[64][68];
    int nb = blockIdx.x * 64, fb = blockIdx.y * 64, b = blockIdx.z;
    int t = threadIdx.x, tr = t >> 4, tc = t & 15;
#pragma unroll
    for (int i = 0; i < 4; ++i) {
        int nl = tr + i * 16;
        size_t fi = (((size_t)(b * N_NODES + nb + nl) * FDIM) + fb + tc * 4) >> 2;
        float4 v = ((const float4*)base)[fi];
        if (p0) { float4 q = ((const float4*)p0)[fi]; v.x = fmaf(c0,q.x,v.x); v.y = fmaf(c0,q.y,v.y); v.z = fmaf(c0,q.z,v.z); v.w = fmaf(c0,q.w,v.w); }
        if (p1) { float4 q = ((const float4*)p1)[fi]; v.x = fmaf(c1,q.x,v.x); v.y = fmaf(c1,q.y,v.y); v.z = fmaf(c1,q.z,v.z); v.w = fmaf(c1,q.w,v.w); }
        if (p2) { float4 q = ((const float4*)p2)[fi]; v.x = fmaf(c2,q.x,v.x); v.y = fmaf(c2,q.y,v.y); v.z = fmaf(c2,q.z,v.z); v.w = fmaf(c2,q.w,v.w); }
        if (p3) { float4 q = ((const float4*)p3)[fi]; v.x = fmaf(c3,q.x,v.x); v.y = fmaf(c3,q.y,v.y); v.z = fmaf(c3,q.z,v.z); v.w = fmaf(c3,q.w,v.w); }
        if (p4) { float4 q = ((const float4*)p4)[fi]; v.x = fmaf(c4,q.x,v.x); v.y = fmaf(c4,q.y,v.y); v.z = fmaf(c4,q.z,v.z); v.w = fmaf(c4,q.w,v.w); }
        ushort4 o = make_ushort4(f2bf(v.x), f2bf(v.y), f2bf(v.z), f2bf(v.w));
        ((ushort4*)yi)[fi] = o;
        tile[nl][tc * 4 + 0] = o.x; tile[nl][tc * 4 + 1] = o.y;
        tile[nl][tc * 4 + 2] = o.z; tile[nl][tc * 4 + 3] = o.w;
    }
    __syncthreads();
#pragma unroll
    for (int i = 0; i < 4; ++i) {
        int fl = tr + i * 16;
        ushort4 o = make_ushort4(tile[tc * 4 + 0][fl], tile[tc * 4 + 1][fl],
                                 tile[tc * 4 + 2][fl], tile[tc * 4 + 3][fl]);
        *(ushort4*)&yiT[((size_t)(b * FDIM + fb + fl) * N_NODES) + nb + tc * 4] = o;
    }
}

// ---------------- bf16 MFMA GEMM: C[M,N] = A[M,K] @ BT[N,K]^T ----------------
// BM x BN tile, BK=64, 4 waves (WM x WN). global_load_lds w/ source-side XOR swizzle.
// BIAS: 0 none; 1 bias[col]; 3 split (col<HDIM: bias[(row>>11)*HDIM+col], else bias2[col-HDIM])
// OBF: 1 -> write bf16, else fp32
template<int BM, int BN, int WM, int WN, int BIAS, int OBF>
__global__ __launch_bounds__(256)
void gemm(const ushort* __restrict__ A, const ushort* __restrict__ BT,
          const float* __restrict__ bias, const float* __restrict__ bias2,
          void* __restrict__ C, int N, int K, long sA, long sB, long sC) {
    constexpr int MR = BM / WM / 16;
    constexpr int NR = BN / WN / 16;
    constexpr int ALD = BM / 32;           // A gloads per thread
    constexpr int BLD = BN / 32;
    __shared__ ushort As[BM * 64];
    __shared__ ushort Bs[BN * 64];
    const ushort* Ag = A + (size_t)blockIdx.z * sA;
    const ushort* Bg = BT + (size_t)blockIdx.z * sB;
    const int tid = threadIdx.x;
    const int lane = tid & 63, wid = tid >> 6;
    const int wn = wid % WN, wm = wid / WN;
    const int r15 = lane & 15, g = lane >> 4;
    const int rowBase = blockIdx.y * BM, colBase = blockIdx.x * BN;

    f32x4 acc[MR][NR];
#pragma unroll
    for (int m = 0; m < MR; ++m)
#pragma unroll
        for (int n = 0; n < NR; ++n) acc[m][n] = (f32x4){0.f, 0.f, 0.f, 0.f};

    for (int k0 = 0; k0 < K; k0 += 64) {
#pragma unroll
        for (int c = 0; c < ALD; ++c) {
            int ci = wid * (ALD * 64) + c * 64 + lane;
            int row = ci >> 3, ch = ci & 7;
            gload16(Ag + (size_t)(rowBase + row) * K + k0 + ((ch ^ (row & 7)) << 3),
                    &As[(wid * (ALD * 64) + c * 64) * 8]);
        }
#pragma unroll
        for (int c = 0; c < BLD; ++c) {
            int ci = wid * (BLD * 64) + c * 64 + lane;
            int row = ci >> 3, ch = ci & 7;
            gload16(Bg + (size_t)(colBase + row) * K + k0 + ((ch ^ (row & 7)) << 3),
                    &Bs[(wid * (BLD * 64) + c * 64) * 8]);
        }
        __syncthreads();
#pragma unroll
        for (int kk = 0; kk < 2; ++kk) {
            bf16x8 af[MR], bfr[NR];
#pragma unroll
            for (int m = 0; m < MR; ++m) {
                int lr = wm * (BM / WM) + m * 16 + r15;
                int off = lr * 128 + ((kk * 64 + g * 16) ^ ((lr & 7) << 4));
                af[m] = *(const bf16x8*)((const char*)As + off);
            }
#pragma unroll
            for (int n = 0; n < NR; ++n) {
                int br = wn * (BN / WN) + n * 16 + r15;
                int off = br * 128 + ((kk * 64 + g * 16) ^ ((br & 7) << 4));
                bfr[n] = *(const bf16x8*)((const char*)Bs + off);
            }
#pragma unroll
            for (int m = 0; m < MR; ++m)
#pragma unroll
                for (int n = 0; n < NR; ++n)
                    acc[m][n] = __builtin_amdgcn_mfma_f32_16x16x32_bf16(
                        af[m], bfr[n], acc[m][n], 0, 0, 0);
        }
        __syncthreads();
    }
#pragma unroll
    for (int m = 0; m < MR; ++m) {
        int row = rowBase + wm * (BM / WM) + m * 16 + g * 4;
#pragma unroll
        for (int n = 0; n < NR; ++n) {
            int col = colBase + wn * (BN / WN) + n * 16 + r15;
            float bv = 0.f;
            if (BIAS == 1) bv = bias[col];
            if (BIAS == 3) bv = (col < HDIM) ? bias[(row >> 11) * HDIM + col]
                                             : bias2[col - HDIM];
#pragma unroll
            for (int r = 0; r < 4; ++r) {
                float v = acc[m][n][r] + bv;
                if (OBF) ((ushort*)C)[(size_t)blockIdx.z * sC + (size_t)(row + r) * N + col] = f2bf(v);
                else     ((float*)C)[(size_t)blockIdx.z * sC + (size_t)(row + r) * N + col] = v;
            }
        }
    }
}

// ---------------- LayerNorm(512)+ReLU, bf16 in (row stride IS) -> bf16 out [.,512] ----
template<int IS>
__global__ __launch_bounds__(256)
void ln_bf(const ushort* __restrict__ in, ushort* __restrict__ out,
           const float* __restrict__ g, const float* __restrict__ b) {
    int row = blockIdx.x, t = threadIdx.x;
    unsigned u = *(const unsigned*)&in[(size_t)row * IS + 2 * t];
    float v0 = bf2f((ushort)(u & 0xffff)), v1 = bf2f((ushort)(u >> 16));
    float s = v0 + v1, s2 = v0 * v0 + v1 * v1;
#pragma unroll
    for (int o = 32; o > 0; o >>= 1) { s += __shfl_down(s, o); s2 += __shfl_down(s2, o); }
    __shared__ float red[8];
    int w = t >> 6;
    if ((t & 63) == 0) { red[w] = s; red[4 + w] = s2; }
    __syncthreads();
    s  = red[0] + red[1] + red[2] + red[3];
    s2 = red[4] + red[5] + red[6] + red[7];
    float mu  = s * (1.f / HDIM);
    float var = fmaf(-mu, mu, s2 * (1.f / HDIM));
    float inv = rsqrtf(var + 1e-5f);
    float n0 = fmaxf(fmaf((v0 - mu) * inv, g[2 * t],     b[2 * t]),     0.f);
    float n1 = fmaxf(fmaf((v1 - mu) * inv, g[2 * t + 1], b[2 * t + 1]), 0.f);
    *(unsigned*)&out[(size_t)row * HDIM + 2 * t] =
        (unsigned)f2bf(n0) | ((unsigned)f2bf(n1) << 16);
}

// ---------------- finish: dcoef = sigmoid(relu(hcat[:,512:768]) . w2 + b2); ks -= dc*Lh ----
__global__ __launch_bounds__(256)
void finish2(const ushort* __restrict__ hcat, const float* __restrict__ w2,
             const float* __restrict__ b2, const float* __restrict__ Lh,
             float* __restrict__ ks) {
    int row = blockIdx.x * 4 + (threadIdx.x >> 6);
    int lane = threadIdx.x & 63;
    ushort4 hv = *(const ushort4*)&hcat[(size_t)row * 768 + 512 + lane * 4];
    float4 wv = ((const float4*)w2)[lane];
    float s = fmaxf(bf2f(hv.x), 0.f) * wv.x + fmaxf(bf2f(hv.y), 0.f) * wv.y +
              fmaxf(bf2f(hv.z), 0.f) * wv.z + fmaxf(bf2f(hv.w), 0.f) * wv.w;
#pragma unroll
    for (int o = 32; o > 0; o >>= 1) s += __shfl_xor(s, o);
    float dc = 1.f / (1.f + expf(-(s + b2[0])));
    size_t i = (size_t)row * 64 + lane;
    float4 a = ((const float4*)ks)[i];
    float4 l = ((const float4*)Lh)[i];
    a.x = fmaf(-dc, l.x, a.x); a.y = fmaf(-dc, l.y, a.y);
    a.z = fmaf(-dc, l.z, a.z); a.w = fmaf(-dc, l.w, a.w);
    ((float4*)ks)[i] = a;
}

__global__ void combine_f32(float* __restrict__ out, const float* __restrict__ base,
                            const float* p0, const float* p1, const float* p2,
                            const float* p3, const float* p4,
                            float c0, float c1, float c2, float c3, float c4) {
    int i = blockIdx.x * blockDim.x + threadIdx.x;
    float4 v = ((const float4*)base)[i];
    if (p0) { float4 q = ((const float4*)p0)[i]; v.x = fmaf(c0,q.x,v.x); v.y = fmaf(c0,q.y,v.y); v.z = fmaf(c0,q.z,v.z); v.w = fmaf(c0,q.w,v.w); }
    if (p1) { float4 q = ((const float4*)p1)[i]; v.x = fmaf(c1,q.x,v.x); v.y = fmaf(c1,q.y,v.y); v.z = fmaf(c1,q.z,v.z); v.w = fmaf(c1,q.w,v.w); }
    if (p2) { float4 q = ((const float4*)p2)[i]; v.x = fmaf(c2,q.x,v.x); v.y = fmaf(c2,q.y,v.y); v.z = fmaf(c2,q.z,v.z); v.w = fmaf(c2,q.w,v.w); }
    if (p3) { float4 q = ((const float4*)p3)[i]; v.x = fmaf(c3,q.x,v.x); v.y = fmaf(c3,q.y,v.y); v.z = fmaf(c3,q.z,v.z); v.w = fmaf(c3,q.w,v.w); }
    if (p4) { float4 q = ((const float4*)p4)[i]; v.x = fmaf(c4,q.x,v.x); v.y = fmaf(c4,q.y,v.y); v.z = fmaf(c4,q.z,v.z); v.w = fmaf(c4,q.w,v.w); }
    ((float4*)out)[i] = v;
}

extern "C" void kernel_launch(void* const* d_in, const int* in_sizes, int n_in,
                              void* d_out, int out_size, void* d_ws, size_t ws_size,
                              hipStream_t stream) {
    const float* state      = (const float*)d_in[0];
    const float* context    = (const float*)d_in[1];
    const float* edge_attr  = (const float*)d_in[2];
    const int*   edge_index = (const int*)d_in[3];
    const float* ew_w1 = (const float*)d_in[4];
    const float* ew_b1 = (const float*)d_in[5];
    const float* ew_w2 = (const float*)d_in[6];
    const float* ew_b2 = (const float*)d_in[7];
    const float* td_w1 = (const float*)d_in[8];
    const float* td_b1 = (const float*)d_in[9];
    const float* ln1_g = (const float*)d_in[10];
    const float* ln1_b = (const float*)d_in[11];
    const float* td_w2 = (const float*)d_in[12];
    const float* td_b2 = (const float*)d_in[13];
    const float* ln2_g = (const float*)d_in[14];
    const float* ln2_b = (const float*)d_in[15];
    const float* td_w3 = (const float*)d_in[16];
    const float* td_b3 = (const float*)d_in[17];
    const float* df_w1 = (const float*)d_in[18];
    const float* df_b1 = (const float*)d_in[19];
    const float* df_w2 = (const float*)d_in[20];
    const float* df_b2 = (const float*)d_in[21];
    float* out = (float*)d_out;

    float* ws = (float*)d_ws;
    size_t off = 0;
    auto alloc = [&](size_t nfloats) { float* p = ws + off; off += nfloats; return p; };
    float*  ew    = alloc(NEDGE);
    float*  deg   = alloc(N_NODES);
    float*  dis   = alloc(N_NODES);
    float*  ctxp  = alloc((size_t)BATCH * HDIM);
    float*  L     = alloc((size_t)N_NODES * N_NODES);                 // 16 MB
    ushort* Lbf   = (ushort*)alloc((size_t)N_NODES * N_NODES / 2);    // 8 MB
    float*  y     = alloc((size_t)BN_ * FDIM);                        // 8 MB
    ushort* yi    = (ushort*)alloc((size_t)BN_ * FDIM / 2);           // 4 MB
    ushort* yiT   = (ushort*)alloc((size_t)BN_ * FDIM / 2);           // 4 MB
    ushort* hcat  = (ushort*)alloc((size_t)BN_ * 768 / 2);            // 12 MB
    ushort* hb1   = (ushort*)alloc((size_t)BN_ * HDIM / 2);           // 8 MB
    ushort* h2b   = (ushort*)alloc((size_t)BN_ * HDIM / 2);           // 8 MB
    float*  Lh    = alloc((size_t)BN_ * FDIM);                        // 8 MB
    ushort* wcat  = (ushort*)alloc((size_t)768 * FDIM / 2);           // [768,256] bf16
    ushort* w2T   = (ushort*)alloc((size_t)HDIM * HDIM / 2);
    ushort* w3T   = (ushort*)alloc((size_t)FDIM * HDIM / 2);
    float* kb[6];
    for (int s = 0; s < 6; ++s) kb[s] = alloc((size_t)BN_ * FDIM);    // 48 MB

    // ---- prep (once per call) ----
    hipMemsetAsync(deg, 0, N_NODES * sizeof(float), stream);
    hipMemsetAsync(L, 0, (size_t)N_NODES * N_NODES * sizeof(float), stream);
    edge_ew_deg<<<NEDGE / 256, 256, 0, stream>>>(edge_attr, edge_index, ew_w1, ew_b1, ew_w2, ew_b2, ew, deg);
    dis_diag<<<N_NODES / 256, 256, 0, stream>>>(deg, dis, L);
    scatter_L<<<NEDGE / 256, 256, 0, stream>>>(edge_index, ew, dis, L);
    cvt_bf16<<<(N_NODES * N_NODES / 4) / 256, 256, 0, stream>>>(L, Lbf);
    ctxproj_kernel<<<BATCH, HDIM, 0, stream>>>(context, td_w1, td_b1, ctxp);
    // wcat rows 0..511 = (td_w1 top half)^T; rows 512..767 = df_w1^T
    transpose_cvt<<<dim3(FDIM / 64, HDIM / 64), 256, 0, stream>>>(td_w1, HDIM, wcat, FDIM, HDIM);
    transpose_cvt<<<dim3(FDIM / 64, FDIM / 64), 256, 0, stream>>>(df_w1, FDIM, wcat + (size_t)HDIM * FDIM, FDIM, FDIM);
    transpose_cvt<<<dim3(HDIM / 64, HDIM / 64), 256, 0, stream>>>(td_w2, HDIM, w2T, HDIM, HDIM);
    transpose_cvt<<<dim3(HDIM / 64, FDIM / 64), 256, 0, stream>>>(td_w3, FDIM, w3T, HDIM, FDIM);

    static const double DPA[6][5] = {
        {0, 0, 0, 0, 0},
        {1.0/5, 0, 0, 0, 0},
        {3.0/40, 9.0/40, 0, 0, 0},
        {44.0/45, -56.0/15, 32.0/9, 0, 0},
        {19372.0/6561, -25360.0/2187, 64448.0/6561, -212.0/729, 0},
        {9017.0/3168, -355.0/33, 46732.0/5247, 49.0/176, -5103.0/18656},
    };

    const int NV4 = BN_ * FDIM / 4;
    const float* ycur = state;
    for (int step = 0; step < 4; ++step) {
        for (int s = 0; s < 6; ++s) {
            const float* p[5] = {nullptr, nullptr, nullptr, nullptr, nullptr};
            float c[5] = {0, 0, 0, 0, 0};
            for (int j = 0; j < s; ++j) { p[j] = kb[j]; c[j] = (float)(DT * DPA[s][j]); }
            combine_yi<<<dim3(N_NODES / 64, FDIM / 64, BATCH), 256, 0, stream>>>(
                ycur, p[0], p[1], p[2], p[3], p[4], c[0], c[1], c[2], c[3], c[4], yi, yiT);
            float* ks = kb[s];
            // merged G1(+ctx bias) & G4(+df_b1): yi @ wcat^T -> hcat bf16 [8192,768]
            gemm<128, 128, 2, 2, 3, 1><<<dim3(768 / 128, BN_ / 128, 1), 256, 0, stream>>>(
                yi, wcat, ctxp, df_b1, hcat, 768, FDIM, 0, 0, 0);
            ln_bf<768><<<BN_, 256, 0, stream>>>(hcat, hb1, ln1_g, ln1_b);
            gemm<64, 128, 1, 4, 1, 1><<<dim3(HDIM / 128, BN_ / 64, 1), 256, 0, stream>>>(
                hb1, w2T, td_b2, nullptr, h2b, HDIM, HDIM, 0, 0, 0);
            ln_bf<512><<<BN_, 256, 0, stream>>>(h2b, h2b, ln2_g, ln2_b);   // in-place
            gemm<64, 64, 2, 2, 1, 0><<<dim3(FDIM / 64, BN_ / 64, 1), 256, 0, stream>>>(
                h2b, w3T, td_b3, nullptr, ks, FDIM, HDIM, 0, 0, 0);
            // diffusion: Lh[b] = L @ y[b]
            gemm<64, 64, 2, 2, 0, 0><<<dim3(FDIM / 64, N_NODES / 64, BATCH), 256, 0, stream>>>(
                Lbf, yiT, nullptr, nullptr, Lh, FDIM, N_NODES,
                0, (long)N_NODES * FDIM, (long)N_NODES * FDIM);
            finish2<<<BN_ / 4, 256, 0, stream>>>(hcat, df_w2, df_b2, Lh, ks);
        }
        float* dst = (step == 3) ? out : y;
        combine_f32<<<NV4 / 256, 256, 0, stream>>>(dst, ycur,
            kb[0], kb[2], kb[3], kb[4], kb[5],
            (float)(DT * 35.0 / 384), (float)(DT * 500.0 / 1113), (float)(DT * 125.0 / 192),
            (float)(DT * -2187.0 / 6784), (float)(DT * 11.0 / 84));
        ycur = y;
    }
    (void)in_sizes; (void)n_in; (void)out_size; (void)ws_size;
}

// Round 9
// 2114.879 us; speedup vs baseline: 4.2022x; 1.0368x over previous
//
#include <hip/hip_runtime.h>
#include <cstddef>
#include <cstdint>

#define N_NODES 2048
#define BATCH   4
#define FDIM    256
#define HDIM    512
#define NEDGE   65536
#define BN_     8192
#define DT      0.25f

typedef __attribute__((ext_vector_type(8))) __bf16 bf16x8;
typedef __attribute__((ext_vector_type(4))) float f32x4;

__device__ __forceinline__ ushort f2bf(float f) {
    union { float f; unsigned u; } v; v.f = f;
    return (ushort)((v.u + 0x7FFF + ((v.u >> 16) & 1)) >> 16);   // RNE
}
__device__ __forceinline__ float bf2f(ushort u) {
    union { float f; unsigned u; } v; v.u = ((unsigned)u) << 16; return v.f;
}
__device__ __forceinline__ void gload16(const void* g, void* l) {
    __builtin_amdgcn_global_load_lds((const __attribute__((address_space(1))) void*)g,
                                     (__attribute__((address_space(3))) void*)l, 16, 0, 0);
}

// ---------------- Laplacian build ----------------
__global__ void edge_ew_deg(const float* __restrict__ attr, const int* __restrict__ eidx,
                            const float* __restrict__ w1, const float* __restrict__ b1,
                            const float* __restrict__ w2, const float* __restrict__ b2,
                            float* __restrict__ ew, float* __restrict__ deg) {
    int e = blockIdx.x * blockDim.x + threadIdx.x;
    if (e >= NEDGE) return;
    float a = attr[e];
    float s = b2[0];
#pragma unroll
    for (int k = 0; k < 32; ++k)
        s += fmaxf(fmaf(a, w1[k], b1[k]), 0.f) * w2[k];
    ew[e] = 1.f / (1.f + expf(-s));
    atomicAdd(&deg[eidx[NEDGE + e]], 1.f);
}

__global__ void dis_diag(const float* __restrict__ deg, float* __restrict__ dis,
                         float* __restrict__ L) {
    int n = blockIdx.x * blockDim.x + threadIdx.x;
    if (n >= N_NODES) return;
    float d = deg[n] + 1.f;
    dis[n] = rsqrtf(d);
    L[(size_t)n * N_NODES + n] = 1.f - 1.f / d;
}

__global__ void scatter_L(const int* __restrict__ eidx, const float* __restrict__ ew,
                          const float* __restrict__ dis, float* __restrict__ L) {
    int e = blockIdx.x * blockDim.x + threadIdx.x;
    if (e >= NEDGE) return;
    int r = eidx[e], c = eidx[NEDGE + e];
    atomicAdd(&L[(size_t)r * N_NODES + c], -dis[r] * ew[e] * dis[c]);
}

__global__ void ctxproj_kernel(const float* __restrict__ ctx, const float* __restrict__ w1,
                               const float* __restrict__ b1, float* __restrict__ out) {
    int b = blockIdx.x, h = threadIdx.x;
    const float* W = w1 + (size_t)FDIM * HDIM + h;
    const float* c = ctx + b * FDIM;
    float s = b1[h];
#pragma unroll 4
    for (int k = 0; k < FDIM; ++k)
        s = fmaf(c[k], W[(size_t)k * HDIM], s);
    out[b * HDIM + h] = s;
}

// out[c*R + r] = bf16(in[r*inStride + c]);  grid (R/64, C/64)
__global__ __launch_bounds__(256)
void transpose_cvt(const float* __restrict__ in, int inStride, ushort* __restrict__ out,
                   int R, int C) {
    __shared__ float tile[64][65];
    int r0 = blockIdx.x * 64, c0 = blockIdx.y * 64;
    int t = threadIdx.x, tr = t >> 4, tc = t & 15;
#pragma unroll
    for (int i = 0; i < 4; ++i) {
        float4 v = *(const float4*)&in[(size_t)(r0 + tr + i * 16) * inStride + c0 + tc * 4];
        tile[tr + i * 16][tc * 4 + 0] = v.x; tile[tr + i * 16][tc * 4 + 1] = v.y;
        tile[tr + i * 16][tc * 4 + 2] = v.z; tile[tr + i * 16][tc * 4 + 3] = v.w;
    }
    __syncthreads();
#pragma unroll
    for (int i = 0; i < 4; ++i) {
        int c = tr + i * 16;
        ushort4 o = make_ushort4(f2bf(tile[tc * 4 + 0][c]), f2bf(tile[tc * 4 + 1][c]),
                                 f2bf(tile[tc * 4 + 2][c]), f2bf(tile[tc * 4 + 3][c]));
        *(ushort4*)&out[(size_t)(c0 + c) * R + r0 + tc * 4] = o;
    }
}

__global__ void cvt_bf16(const float* __restrict__ in, ushort* __restrict__ out) {
    int i = blockIdx.x * blockDim.x + threadIdx.x;
    float4 v = ((const float4*)in)[i];
    ((ushort4*)out)[i] = make_ushort4(f2bf(v.x), f2bf(v.y), f2bf(v.z), f2bf(v.w));
}

// ---------------- combine: v = base + sum c_j * bf16(k_j); write [dstf fp32] [yi bf16] [yiT] ----
// grid (N_NODES/64, FDIM/64, BATCH), 256 thr. k buffers are bf16.
__global__ __launch_bounds__(256)
void combine_all(const float* __restrict__ base,
                 const ushort* p0, const ushort* p1, const ushort* p2,
                 const ushort* p3, const ushort* p4,
                 float c0, float c1, float c2, float c3, float c4,
                 float* __restrict__ dstf, ushort* __restrict__ yi,
                 ushort* __restrict__ yiT) {
    __shared__ ushort tile[64][68];
    int nb = blockIdx.x * 64, fb = blockIdx.y * 64, b = blockIdx.z;
    int t = threadIdx.x, tr = t >> 4, tc = t & 15;
#pragma unroll
    for (int i = 0; i < 4; ++i) {
        int nl = tr + i * 16;
        size_t fi = (((size_t)(b * N_NODES + nb + nl) * FDIM) + fb + tc * 4) >> 2;
        float4 v = ((const float4*)base)[fi];
        if (p0) { ushort4 q = ((const ushort4*)p0)[fi]; v.x = fmaf(c0,bf2f(q.x),v.x); v.y = fmaf(c0,bf2f(q.y),v.y); v.z = fmaf(c0,bf2f(q.z),v.z); v.w = fmaf(c0,bf2f(q.w),v.w); }
        if (p1) { ushort4 q = ((const ushort4*)p1)[fi]; v.x = fmaf(c1,bf2f(q.x),v.x); v.y = fmaf(c1,bf2f(q.y),v.y); v.z = fmaf(c1,bf2f(q.z),v.z); v.w = fmaf(c1,bf2f(q.w),v.w); }
        if (p2) { ushort4 q = ((const ushort4*)p2)[fi]; v.x = fmaf(c2,bf2f(q.x),v.x); v.y = fmaf(c2,bf2f(q.y),v.y); v.z = fmaf(c2,bf2f(q.z),v.z); v.w = fmaf(c2,bf2f(q.w),v.w); }
        if (p3) { ushort4 q = ((const ushort4*)p3)[fi]; v.x = fmaf(c3,bf2f(q.x),v.x); v.y = fmaf(c3,bf2f(q.y),v.y); v.z = fmaf(c3,bf2f(q.z),v.z); v.w = fmaf(c3,bf2f(q.w),v.w); }
        if (p4) { ushort4 q = ((const ushort4*)p4)[fi]; v.x = fmaf(c4,bf2f(q.x),v.x); v.y = fmaf(c4,bf2f(q.y),v.y); v.z = fmaf(c4,bf2f(q.z),v.z); v.w = fmaf(c4,bf2f(q.w),v.w); }
        if (dstf) ((float4*)dstf)[fi] = v;
        ushort4 o = make_ushort4(f2bf(v.x), f2bf(v.y), f2bf(v.z), f2bf(v.w));
        if (yi) ((ushort4*)yi)[fi] = o;
        tile[nl][tc * 4 + 0] = o.x; tile[nl][tc * 4 + 1] = o.y;
        tile[nl][tc * 4 + 2] = o.z; tile[nl][tc * 4 + 3] = o.w;
    }
    __syncthreads();
    if (!yiT) return;
#pragma unroll
    for (int i = 0; i < 4; ++i) {
        int fl = tr + i * 16;
        ushort4 o = make_ushort4(tile[tc * 4 + 0][fl], tile[tc * 4 + 1][fl],
                                 tile[tc * 4 + 2][fl], tile[tc * 4 + 3][fl]);
        *(ushort4*)&yiT[((size_t)(b * FDIM + fb + fl) * N_NODES) + nb + tc * 4] = o;
    }
}

// ---------------- bf16 MFMA GEMM: C[M,N] = A[M,K] @ BT[N,K]^T ----------------
// BIAS: 0 none; 1 bias[col]; 3 split (col<HDIM: bias[(row>>11)*HDIM+col], else bias2[col-HDIM])
// EPI: 0 fp32 store; 1 bf16 store; 2 diffusion RMW: ks[(b*2048+n)*256+f] -= dc[b*2048+n]*acc
//      (EPI==2: C = ushort* ks, bias2 = dc, col = b*256+f with N=1024)
template<int BM, int BN, int WM, int WN, int BIAS, int EPI>
__global__ __launch_bounds__(256)
void gemm(const ushort* __restrict__ A, const ushort* __restrict__ BT,
          const float* __restrict__ bias, const float* __restrict__ bias2,
          void* __restrict__ C, int N, int K, long sA, long sB, long sC) {
    constexpr int MR = BM / WM / 16;
    constexpr int NR = BN / WN / 16;
    constexpr int ALD = BM / 32;
    constexpr int BLD = BN / 32;
    __shared__ ushort As[BM * 64];
    __shared__ ushort Bs[BN * 64];
    const ushort* Ag = A + (size_t)blockIdx.z * sA;
    const ushort* Bg = BT + (size_t)blockIdx.z * sB;
    const int tid = threadIdx.x;
    const int lane = tid & 63, wid = tid >> 6;
    const int wn = wid % WN, wm = wid / WN;
    const int r15 = lane & 15, g = lane >> 4;
    const int rowBase = blockIdx.y * BM, colBase = blockIdx.x * BN;

    f32x4 acc[MR][NR];
#pragma unroll
    for (int m = 0; m < MR; ++m)
#pragma unroll
        for (int n = 0; n < NR; ++n) acc[m][n] = (f32x4){0.f, 0.f, 0.f, 0.f};

    for (int k0 = 0; k0 < K; k0 += 64) {
#pragma unroll
        for (int c = 0; c < ALD; ++c) {
            int ci = wid * (ALD * 64) + c * 64 + lane;
            int row = ci >> 3, ch = ci & 7;
            gload16(Ag + (size_t)(rowBase + row) * K + k0 + ((ch ^ (row & 7)) << 3),
                    &As[(wid * (ALD * 64) + c * 64) * 8]);
        }
#pragma unroll
        for (int c = 0; c < BLD; ++c) {
            int ci = wid * (BLD * 64) + c * 64 + lane;
            int row = ci >> 3, ch = ci & 7;
            gload16(Bg + (size_t)(colBase + row) * K + k0 + ((ch ^ (row & 7)) << 3),
                    &Bs[(wid * (BLD * 64) + c * 64) * 8]);
        }
        __syncthreads();
#pragma unroll
        for (int kk = 0; kk < 2; ++kk) {
            bf16x8 af[MR], bfr[NR];
#pragma unroll
            for (int m = 0; m < MR; ++m) {
                int lr = wm * (BM / WM) + m * 16 + r15;
                int off = lr * 128 + ((kk * 64 + g * 16) ^ ((lr & 7) << 4));
                af[m] = *(const bf16x8*)((const char*)As + off);
            }
#pragma unroll
            for (int n = 0; n < NR; ++n) {
                int br = wn * (BN / WN) + n * 16 + r15;
                int off = br * 128 + ((kk * 64 + g * 16) ^ ((br & 7) << 4));
                bfr[n] = *(const bf16x8*)((const char*)Bs + off);
            }
#pragma unroll
            for (int m = 0; m < MR; ++m)
#pragma unroll
                for (int n = 0; n < NR; ++n)
                    acc[m][n] = __builtin_amdgcn_mfma_f32_16x16x32_bf16(
                        af[m], bfr[n], acc[m][n], 0, 0, 0);
        }
        __syncthreads();
    }
    if (EPI == 2) {
        int b = colBase >> 8;
        ushort* ks = (ushort*)C;
#pragma unroll
        for (int m = 0; m < MR; ++m) {
            int row = rowBase + wm * (BM / WM) + m * 16 + g * 4;
            float4 dcv = *(const float4*)&bias2[b * N_NODES + row];
            float dca[4] = {dcv.x, dcv.y, dcv.z, dcv.w};
#pragma unroll
            for (int n = 0; n < NR; ++n) {
                int col = colBase + wn * (BN / WN) + n * 16 + r15;
                int f = col & 255;
#pragma unroll
                for (int r = 0; r < 4; ++r) {
                    size_t idx = ((size_t)(b * N_NODES + row + r)) * 256 + f;
                    ks[idx] = f2bf(bf2f(ks[idx]) - dca[r] * acc[m][n][r]);
                }
            }
        }
        return;
    }
#pragma unroll
    for (int m = 0; m < MR; ++m) {
        int row = rowBase + wm * (BM / WM) + m * 16 + g * 4;
#pragma unroll
        for (int n = 0; n < NR; ++n) {
            int col = colBase + wn * (BN / WN) + n * 16 + r15;
            float bv = 0.f;
            if (BIAS == 1) bv = bias[col];
            if (BIAS == 3) bv = (col < HDIM) ? bias[(row >> 11) * HDIM + col]
                                             : bias2[col - HDIM];
#pragma unroll
            for (int r = 0; r < 4; ++r) {
                float v = acc[m][n][r] + bv;
                if (EPI == 1) ((ushort*)C)[(size_t)blockIdx.z * sC + (size_t)(row + r) * N + col] = f2bf(v);
                else          ((float*)C)[(size_t)blockIdx.z * sC + (size_t)(row + r) * N + col] = v;
            }
        }
    }
}

// ---------------- LayerNorm(512)+ReLU, bf16 in (row stride IS) -> bf16 out [.,512] ----
template<int IS>
__global__ __launch_bounds__(256)
void ln_bf(const ushort* __restrict__ in, ushort* __restrict__ out,
           const float* __restrict__ g, const float* __restrict__ b) {
    int row = blockIdx.x, t = threadIdx.x;
    unsigned u = *(const unsigned*)&in[(size_t)row * IS + 2 * t];
    float v0 = bf2f((ushort)(u & 0xffff)), v1 = bf2f((ushort)(u >> 16));
    float s = v0 + v1, s2 = v0 * v0 + v1 * v1;
#pragma unroll
    for (int o = 32; o > 0; o >>= 1) { s += __shfl_down(s, o); s2 += __shfl_down(s2, o); }
    __shared__ float red[8];
    int w = t >> 6;
    if ((t & 63) == 0) { red[w] = s; red[4 + w] = s2; }
    __syncthreads();
    s  = red[0] + red[1] + red[2] + red[3];
    s2 = red[4] + red[5] + red[6] + red[7];
    float mu  = s * (1.f / HDIM);
    float var = fmaf(-mu, mu, s2 * (1.f / HDIM));
    float inv = rsqrtf(var + 1e-5f);
    float n0 = fmaxf(fmaf((v0 - mu) * inv, g[2 * t],     b[2 * t]),     0.f);
    float n1 = fmaxf(fmaf((v1 - mu) * inv, g[2 * t + 1], b[2 * t + 1]), 0.f);
    *(unsigned*)&out[(size_t)row * HDIM + 2 * t] =
        (unsigned)f2bf(n0) | ((unsigned)f2bf(n1) << 16);
}

// ---------------- dc[row] = sigmoid(relu(hcat[row,512:768]) . w2 + b2) ----------------
__global__ __launch_bounds__(256)
void dcoef_kernel(const ushort* __restrict__ hcat, const float* __restrict__ w2,
                  const float* __restrict__ b2, float* __restrict__ dc) {
    int row = blockIdx.x * 4 + (threadIdx.x >> 6);
    int lane = threadIdx.x & 63;
    ushort4 hv = *(const ushort4*)&hcat[(size_t)row * 768 + 512 + lane * 4];
    float4 wv = ((const float4*)w2)[lane];
    float s = fmaxf(bf2f(hv.x), 0.f) * wv.x + fmaxf(bf2f(hv.y), 0.f) * wv.y +
              fmaxf(bf2f(hv.z), 0.f) * wv.z + fmaxf(bf2f(hv.w), 0.f) * wv.w;
#pragma unroll
    for (int o = 32; o > 0; o >>= 1) s += __shfl_xor(s, o);
    if (lane == 0) dc[row] = 1.f / (1.f + expf(-(s + b2[0])));
}

extern "C" void kernel_launch(void* const* d_in, const int* in_sizes, int n_in,
                              void* d_out, int out_size, void* d_ws, size_t ws_size,
                              hipStream_t stream) {
    const float* state      = (const float*)d_in[0];
    const float* context    = (const float*)d_in[1];
    const float* edge_attr  = (const float*)d_in[2];
    const int*   edge_index = (const int*)d_in[3];
    const float* ew_w1 = (const float*)d_in[4];
    const float* ew_b1 = (const float*)d_in[5];
    const float* ew_w2 = (const float*)d_in[6];
    const float* ew_b2 = (const float*)d_in[7];
    const float* td_w1 = (const float*)d_in[8];
    const float* td_b1 = (const float*)d_in[9];
    const float* ln1_g = (const float*)d_in[10];
    const float* ln1_b = (const float*)d_in[11];
    const float* td_w2 = (const float*)d_in[12];
    const float* td_b2 = (const float*)d_in[13];
    const float* ln2_g = (const float*)d_in[14];
    const float* ln2_b = (const float*)d_in[15];
    const float* td_w3 = (const float*)d_in[16];
    const float* td_b3 = (const float*)d_in[17];
    const float* df_w1 = (const float*)d_in[18];
    const float* df_b1 = (const float*)d_in[19];
    const float* df_w2 = (const float*)d_in[20];
    const float* df_b2 = (const float*)d_in[21];
    float* out = (float*)d_out;

    float* ws = (float*)d_ws;
    size_t off = 0;
    auto alloc = [&](size_t nfloats) { float* p = ws + off; off += nfloats; return p; };
    float*  ew    = alloc(NEDGE);
    float*  deg   = alloc(N_NODES);
    float*  dis   = alloc(N_NODES);
    float*  ctxp  = alloc((size_t)BATCH * HDIM);
    float*  dc    = alloc(BN_);
    float*  L     = alloc((size_t)N_NODES * N_NODES);                 // 16 MB
    ushort* Lbf   = (ushort*)alloc((size_t)N_NODES * N_NODES / 2);    // 8 MB
    float*  y     = alloc((size_t)BN_ * FDIM);                        // 8 MB
    ushort* yi    = (ushort*)alloc((size_t)BN_ * FDIM / 2);           // 4 MB
    ushort* yiT   = (ushort*)alloc((size_t)BN_ * FDIM / 2);           // 4 MB
    ushort* hcat  = (ushort*)alloc((size_t)BN_ * 768 / 2);            // 12 MB
    ushort* hb1   = (ushort*)alloc((size_t)BN_ * HDIM / 2);           // 8 MB
    ushort* h2b   = (ushort*)alloc((size_t)BN_ * HDIM / 2);           // 8 MB
    ushort* wcat  = (ushort*)alloc((size_t)768 * FDIM / 2);
    ushort* w2T   = (ushort*)alloc((size_t)HDIM * HDIM / 2);
    ushort* w3T   = (ushort*)alloc((size_t)FDIM * HDIM / 2);
    ushort* kb[6];
    for (int s = 0; s < 6; ++s) kb[s] = (ushort*)alloc((size_t)BN_ * FDIM / 2);  // 4 MB each

    // ---- prep (once per call) ----
    hipMemsetAsync(deg, 0, N_NODES * sizeof(float), stream);
    hipMemsetAsync(L, 0, (size_t)N_NODES * N_NODES * sizeof(float), stream);
    edge_ew_deg<<<NEDGE / 256, 256, 0, stream>>>(edge_attr, edge_index, ew_w1, ew_b1, ew_w2, ew_b2, ew, deg);
    dis_diag<<<N_NODES / 256, 256, 0, stream>>>(deg, dis, L);
    scatter_L<<<NEDGE / 256, 256, 0, stream>>>(edge_index, ew, dis, L);
    cvt_bf16<<<(N_NODES * N_NODES / 4) / 256, 256, 0, stream>>>(L, Lbf);
    ctxproj_kernel<<<BATCH, HDIM, 0, stream>>>(context, td_w1, td_b1, ctxp);
    transpose_cvt<<<dim3(FDIM / 64, HDIM / 64), 256, 0, stream>>>(td_w1, HDIM, wcat, FDIM, HDIM);
    transpose_cvt<<<dim3(FDIM / 64, FDIM / 64), 256, 0, stream>>>(df_w1, FDIM, wcat + (size_t)HDIM * FDIM, FDIM, FDIM);
    transpose_cvt<<<dim3(HDIM / 64, HDIM / 64), 256, 0, stream>>>(td_w2, HDIM, w2T, HDIM, HDIM);
    transpose_cvt<<<dim3(HDIM / 64, FDIM / 64), 256, 0, stream>>>(td_w3, FDIM, w3T, HDIM, FDIM);

    static const double DPA[6][5] = {
        {0, 0, 0, 0, 0},
        {1.0/5, 0, 0, 0, 0},
        {3.0/40, 9.0/40, 0, 0, 0},
        {44.0/45, -56.0/15, 32.0/9, 0, 0},
        {19372.0/6561, -25360.0/2187, 64448.0/6561, -212.0/729, 0},
        {9017.0/3168, -355.0/33, 46732.0/5247, 49.0/176, -5103.0/18656},
    };

    const dim3 cgrid(N_NODES / 64, FDIM / 64, BATCH);
    const float* ycur = state;
    for (int step = 0; step < 4; ++step) {
        for (int s = 0; s < 6; ++s) {
            if (s == 0) {
                if (step == 0)   // later steps: yi/yiT already written by step-final combine
                    combine_all<<<cgrid, 256, 0, stream>>>(ycur, nullptr, nullptr, nullptr,
                        nullptr, nullptr, 0, 0, 0, 0, 0, nullptr, yi, yiT);
            } else {
                const ushort* p[5] = {nullptr, nullptr, nullptr, nullptr, nullptr};
                float c[5] = {0, 0, 0, 0, 0};
                for (int j = 0; j < s; ++j) { p[j] = kb[j]; c[j] = (float)(DT * DPA[s][j]); }
                combine_all<<<cgrid, 256, 0, stream>>>(ycur, p[0], p[1], p[2], p[3], p[4],
                    c[0], c[1], c[2], c[3], c[4], nullptr, yi, yiT);
            }
            ushort* ks = kb[s];
            // merged G1(+ctx bias) & G4(+df_b1): yi @ wcat^T -> hcat bf16 [8192,768]
            gemm<128, 128, 2, 2, 3, 1><<<dim3(768 / 128, BN_ / 128, 1), 256, 0, stream>>>(
                yi, wcat, ctxp, df_b1, hcat, 768, FDIM, 0, 0, 0);
            ln_bf<768><<<BN_, 256, 0, stream>>>(hcat, hb1, ln1_g, ln1_b);
            dcoef_kernel<<<BN_ / 4, 256, 0, stream>>>(hcat, df_w2, df_b2, dc);
            gemm<64, 128, 1, 4, 1, 1><<<dim3(HDIM / 128, BN_ / 64, 1), 256, 0, stream>>>(
                hb1, w2T, td_b2, nullptr, h2b, HDIM, HDIM, 0, 0, 0);
            ln_bf<512><<<BN_, 256, 0, stream>>>(h2b, h2b, ln2_g, ln2_b);
            gemm<64, 64, 2, 2, 1, 1><<<dim3(FDIM / 64, BN_ / 64, 1), 256, 0, stream>>>(
                h2b, w3T, td_b3, nullptr, ks, FDIM, HDIM, 0, 0, 0);
            // merged diffusion over batches: [2048,2048] @ yiT^T -> RMW ks -= dc*Lh
            gemm<64, 64, 2, 2, 0, 2><<<dim3(1024 / 64, N_NODES / 64, 1), 256, 0, stream>>>(
                Lbf, yiT, nullptr, dc, ks, 1024, N_NODES, 0, 0, 0);
        }
        // step-final: y_{n+1} fp32 (+ yi/yiT for next step's stage 0)
        float* dstf = (step == 3) ? out : y;
        combine_all<<<cgrid, 256, 0, stream>>>(ycur,
            kb[0], kb[2], kb[3], kb[4], kb[5],
            (float)(DT * 35.0 / 384), (float)(DT * 500.0 / 1113), (float)(DT * 125.0 / 192),
            (float)(DT * -2187.0 / 6784), (float)(DT * 11.0 / 84),
            dstf, (step == 3) ? nullptr : yi, (step == 3) ? nullptr : yiT);
        ycur = y;
    }
    (void)in_sizes; (void)n_in; (void)out_size; (void)ws_size;
}

// Round 11
// 1973.070 us; speedup vs baseline: 4.5042x; 1.0719x over previous
//
#include <hip/hip_runtime.h>
#include <cstddef>
#include <cstdint>

#define N_NODES 2048
#define BATCH   4
#define FDIM    256
#define HDIM    512
#define NEDGE   65536
#define BN_     8192
#define DT      0.25f

typedef __attribute__((ext_vector_type(8))) __bf16 bf16x8;
typedef __attribute__((ext_vector_type(4))) float f32x4;

__device__ __forceinline__ ushort f2bf(float f) {
    union { float f; unsigned u; } v; v.f = f;
    return (ushort)((v.u + 0x7FFF + ((v.u >> 16) & 1)) >> 16);   // RNE
}
__device__ __forceinline__ float bf2f(ushort u) {
    union { float f; unsigned u; } v; v.u = ((unsigned)u) << 16; return v.f;
}
__device__ __forceinline__ void gload16(const void* g, void* l) {
    __builtin_amdgcn_global_load_lds((const __attribute__((address_space(1))) void*)g,
                                     (__attribute__((address_space(3))) void*)l, 16, 0, 0);
}

// ---------------- Laplacian build ----------------
__global__ void edge_ew_deg(const float* __restrict__ attr, const int* __restrict__ eidx,
                            const float* __restrict__ w1, const float* __restrict__ b1,
                            const float* __restrict__ w2, const float* __restrict__ b2,
                            float* __restrict__ ew, float* __restrict__ deg) {
    int e = blockIdx.x * blockDim.x + threadIdx.x;
    if (e >= NEDGE) return;
    float a = attr[e];
    float s = b2[0];
#pragma unroll
    for (int k = 0; k < 32; ++k)
        s += fmaxf(fmaf(a, w1[k], b1[k]), 0.f) * w2[k];
    ew[e] = 1.f / (1.f + expf(-s));
    atomicAdd(&deg[eidx[NEDGE + e]], 1.f);
}

__global__ void dis_diag(const float* __restrict__ deg, float* __restrict__ dis,
                         float* __restrict__ L) {
    int n = blockIdx.x * blockDim.x + threadIdx.x;
    if (n >= N_NODES) return;
    float d = deg[n] + 1.f;
    dis[n] = rsqrtf(d);
    L[(size_t)n * N_NODES + n] = 1.f - 1.f / d;
}

__global__ void scatter_L(const int* __restrict__ eidx, const float* __restrict__ ew,
                          const float* __restrict__ dis, float* __restrict__ L) {
    int e = blockIdx.x * blockDim.x + threadIdx.x;
    if (e >= NEDGE) return;
    int r = eidx[e], c = eidx[NEDGE + e];
    atomicAdd(&L[(size_t)r * N_NODES + c], -dis[r] * ew[e] * dis[c]);
}

__global__ void ctxproj_kernel(const float* __restrict__ ctx, const float* __restrict__ w1,
                               const float* __restrict__ b1, float* __restrict__ out) {
    int b = blockIdx.x, h = threadIdx.x;
    const float* W = w1 + (size_t)FDIM * HDIM + h;
    const float* c = ctx + b * FDIM;
    float s = b1[h];
#pragma unroll 4
    for (int k = 0; k < FDIM; ++k)
        s = fmaf(c[k], W[(size_t)k * HDIM], s);
    out[b * HDIM + h] = s;
}

// out[c*R + r] = bf16(in[r*inStride + c]);  grid (R/64, C/64)
__global__ __launch_bounds__(256)
void transpose_cvt(const float* __restrict__ in, int inStride, ushort* __restrict__ out,
                   int R, int C) {
    __shared__ float tile[64][65];
    int r0 = blockIdx.x * 64, c0 = blockIdx.y * 64;
    int t = threadIdx.x, tr = t >> 4, tc = t & 15;
#pragma unroll
    for (int i = 0; i < 4; ++i) {
        float4 v = *(const float4*)&in[(size_t)(r0 + tr + i * 16) * inStride + c0 + tc * 4];
        tile[tr + i * 16][tc * 4 + 0] = v.x; tile[tr + i * 16][tc * 4 + 1] = v.y;
        tile[tr + i * 16][tc * 4 + 2] = v.z; tile[tr + i * 16][tc * 4 + 3] = v.w;
    }
    __syncthreads();
#pragma unroll
    for (int i = 0; i < 4; ++i) {
        int c = tr + i * 16;
        ushort4 o = make_ushort4(f2bf(tile[tc * 4 + 0][c]), f2bf(tile[tc * 4 + 1][c]),
                                 f2bf(tile[tc * 4 + 2][c]), f2bf(tile[tc * 4 + 3][c]));
        *(ushort4*)&out[(size_t)(c0 + c) * R + r0 + tc * 4] = o;
    }
}

__global__ void cvt_bf16(const float* __restrict__ in, ushort* __restrict__ out) {
    int i = blockIdx.x * blockDim.x + threadIdx.x;
    float4 v = ((const float4*)in)[i];
    ((ushort4*)out)[i] = make_ushort4(f2bf(v.x), f2bf(v.y), f2bf(v.z), f2bf(v.w));
}

// ---------------- combine: v = base + sum c_j * bf16(k_j); write [dstf fp32] [yi bf16] [yiT] ----
__global__ __launch_bounds__(256)
void combine_all(const float* __restrict__ base,
                 const ushort* p0, const ushort* p1, const ushort* p2,
                 const ushort* p3, const ushort* p4,
                 float c0, float c1, float c2, float c3, float c4,
                 float* __restrict__ dstf, ushort* __restrict__ yi,
                 ushort* __restrict__ yiT) {
    __shared__ ushort tile[64][68];
    int nb = blockIdx.x * 64, fb = blockIdx.y * 64, b = blockIdx.z;
    int t = threadIdx.x, tr = t >> 4, tc = t & 15;
#pragma unroll
    for (int i = 0; i < 4; ++i) {
        int nl = tr + i * 16;
        size_t fi = (((size_t)(b * N_NODES + nb + nl) * FDIM) + fb + tc * 4) >> 2;
        float4 v = ((const float4*)base)[fi];
        if (p0) { ushort4 q = ((const ushort4*)p0)[fi]; v.x = fmaf(c0,bf2f(q.x),v.x); v.y = fmaf(c0,bf2f(q.y),v.y); v.z = fmaf(c0,bf2f(q.z),v.z); v.w = fmaf(c0,bf2f(q.w),v.w); }
        if (p1) { ushort4 q = ((const ushort4*)p1)[fi]; v.x = fmaf(c1,bf2f(q.x),v.x); v.y = fmaf(c1,bf2f(q.y),v.y); v.z = fmaf(c1,bf2f(q.z),v.z); v.w = fmaf(c1,bf2f(q.w),v.w); }
        if (p2) { ushort4 q = ((const ushort4*)p2)[fi]; v.x = fmaf(c2,bf2f(q.x),v.x); v.y = fmaf(c2,bf2f(q.y),v.y); v.z = fmaf(c2,bf2f(q.z),v.z); v.w = fmaf(c2,bf2f(q.w),v.w); }
        if (p3) { ushort4 q = ((const ushort4*)p3)[fi]; v.x = fmaf(c3,bf2f(q.x),v.x); v.y = fmaf(c3,bf2f(q.y),v.y); v.z = fmaf(c3,bf2f(q.z),v.z); v.w = fmaf(c3,bf2f(q.w),v.w); }
        if (p4) { ushort4 q = ((const ushort4*)p4)[fi]; v.x = fmaf(c4,bf2f(q.x),v.x); v.y = fmaf(c4,bf2f(q.y),v.y); v.z = fmaf(c4,bf2f(q.z),v.z); v.w = fmaf(c4,bf2f(q.w),v.w); }
        if (dstf) ((float4*)dstf)[fi] = v;
        ushort4 o = make_ushort4(f2bf(v.x), f2bf(v.y), f2bf(v.z), f2bf(v.w));
        if (yi) ((ushort4*)yi)[fi] = o;
        tile[nl][tc * 4 + 0] = o.x; tile[nl][tc * 4 + 1] = o.y;
        tile[nl][tc * 4 + 2] = o.z; tile[nl][tc * 4 + 3] = o.w;
    }
    __syncthreads();
    if (!yiT) return;
#pragma unroll
    for (int i = 0; i < 4; ++i) {
        int fl = tr + i * 16;
        ushort4 o = make_ushort4(tile[tc * 4 + 0][fl], tile[tc * 4 + 1][fl],
                                 tile[tc * 4 + 2][fl], tile[tc * 4 + 3][fl]);
        *(ushort4*)&yiT[((size_t)(b * FDIM + fb + fl) * N_NODES) + nb + tc * 4] = o;
    }
}

// ---------------- bf16 MFMA GEMM: C[M,N] = A[M,K] @ BT[N,K]^T ----------------
// BK in {64,128}. Source-side XOR swizzle (chunk ^= row&7), matching read-side byte XOR.
// BIAS: 0 none; 1 bias[col]; 3 split (col<HDIM: bias[(row>>11)*HDIM+col], else bias2[col-HDIM])
// EPI: 0 fp32 store; 1 bf16 store; 2 diffusion RMW: ks[(b*2048+n)*256+f] -= dc[b*2048+n]*acc
template<int BM, int BN, int BK, int WM, int WN, int BIAS, int EPI>
__global__ __launch_bounds__(256)
void gemm(const ushort* __restrict__ A, const ushort* __restrict__ BT,
          const float* __restrict__ bias, const float* __restrict__ bias2,
          void* __restrict__ C, int N, int K, long sA, long sB, long sC) {
    constexpr int MR  = BM / WM / 16;
    constexpr int NR  = BN / WN / 16;
    constexpr int CPR = BK / 8;               // 16B chunks per row
    constexpr int ALD = BM * CPR / 256;       // staging iters (A)
    constexpr int BLD = BN * CPR / 256;
    constexpr int KK  = BK / 32;              // mfma K-steps per tile
    __shared__ ushort As[BM * BK];
    __shared__ ushort Bs[BN * BK];
    const ushort* Ag = A + (size_t)blockIdx.z * sA;
    const ushort* Bg = BT + (size_t)blockIdx.z * sB;
    const int tid = threadIdx.x;
    const int lane = tid & 63, wid = tid >> 6;
    const int wn = wid % WN, wm = wid / WN;
    const int r15 = lane & 15, g = lane >> 4;
    const int rowBase = blockIdx.y * BM, colBase = blockIdx.x * BN;

    f32x4 acc[MR][NR];
#pragma unroll
    for (int m = 0; m < MR; ++m)
#pragma unroll
        for (int n = 0; n < NR; ++n) acc[m][n] = (f32x4){0.f, 0.f, 0.f, 0.f};

    for (int k0 = 0; k0 < K; k0 += BK) {
#pragma unroll
        for (int c = 0; c < ALD; ++c) {
            int ci = (wid * ALD + c) * 64 + lane;
            int row = ci / CPR, ch = ci % CPR;
            gload16(Ag + (size_t)(rowBase + row) * K + k0 + ((ch ^ (row & 7)) << 3),
                    &As[((wid * ALD + c) * 64) * 8]);
        }
#pragma unroll
        for (int c = 0; c < BLD; ++c) {
            int ci = (wid * BLD + c) * 64 + lane;
            int row = ci / CPR, ch = ci % CPR;
            gload16(Bg + (size_t)(colBase + row) * K + k0 + ((ch ^ (row & 7)) << 3),
                    &Bs[((wid * BLD + c) * 64) * 8]);
        }
        __syncthreads();                      // drains vmcnt before barrier
#pragma unroll
        for (int kk = 0; kk < KK; ++kk) {
            bf16x8 af[MR], bfr[NR];
#pragma unroll
            for (int m = 0; m < MR; ++m) {
                int lr = wm * (BM / WM) + m * 16 + r15;
                int off = lr * (BK * 2) + ((kk * 64 + g * 16) ^ ((lr & 7) << 4));
                af[m] = *(const bf16x8*)((const char*)As + off);
            }
#pragma unroll
            for (int n = 0; n < NR; ++n) {
                int br = wn * (BN / WN) + n * 16 + r15;
                int off = br * (BK * 2) + ((kk * 64 + g * 16) ^ ((br & 7) << 4));
                bfr[n] = *(const bf16x8*)((const char*)Bs + off);
            }
#pragma unroll
            for (int m = 0; m < MR; ++m)
#pragma unroll
                for (int n = 0; n < NR; ++n)
                    acc[m][n] = __builtin_amdgcn_mfma_f32_16x16x32_bf16(
                        af[m], bfr[n], acc[m][n], 0, 0, 0);
        }
        __syncthreads();
    }
    if (EPI == 2) {
        int b = colBase >> 8;
        ushort* ks = (ushort*)C;
#pragma unroll
        for (int m = 0; m < MR; ++m) {
            int row = rowBase + wm * (BM / WM) + m * 16 + g * 4;
            float4 dcv = *(const float4*)&bias2[b * N_NODES + row];
            float dca[4] = {dcv.x, dcv.y, dcv.z, dcv.w};
#pragma unroll
            for (int n = 0; n < NR; ++n) {
                int col = colBase + wn * (BN / WN) + n * 16 + r15;
                int f = col & 255;
#pragma unroll
                for (int r = 0; r < 4; ++r) {
                    size_t idx = ((size_t)(b * N_NODES + row + r)) * 256 + f;
                    ks[idx] = f2bf(bf2f(ks[idx]) - dca[r] * acc[m][n][r]);
                }
            }
        }
        return;
    }
#pragma unroll
    for (int m = 0; m < MR; ++m) {
        int row = rowBase + wm * (BM / WM) + m * 16 + g * 4;
#pragma unroll
        for (int n = 0; n < NR; ++n) {
            int col = colBase + wn * (BN / WN) + n * 16 + r15;
            float bv = 0.f;
            if (BIAS == 1) bv = bias[col];
            if (BIAS == 3) bv = (col < HDIM) ? bias[(row >> 11) * HDIM + col]
                                             : bias2[col - HDIM];
#pragma unroll
            for (int r = 0; r < 4; ++r) {
                float v = acc[m][n][r] + bv;
                if (EPI == 1) ((ushort*)C)[(size_t)blockIdx.z * sC + (size_t)(row + r) * N + col] = f2bf(v);
                else          ((float*)C)[(size_t)blockIdx.z * sC + (size_t)(row + r) * N + col] = v;
            }
        }
    }
}

// ---------------- fused LN(cols 0:512)+ReLU -> out  AND  dcoef(cols 512:768) -> dc ----
__global__ __launch_bounds__(256)
void ln_dc_768(const ushort* __restrict__ hcat, ushort* __restrict__ out,
               const float* __restrict__ g, const float* __restrict__ b,
               const float* __restrict__ w2, const float* __restrict__ b2,
               float* __restrict__ dc) {
    int row = blockIdx.x, t = threadIdx.x;
    const ushort* hrow = hcat + (size_t)row * 768;
    unsigned u = *(const unsigned*)&hrow[2 * t];
    float v0 = bf2f((ushort)(u & 0xffff)), v1 = bf2f((ushort)(u >> 16));
    float d = fmaxf(bf2f(hrow[512 + t]), 0.f) * w2[t];
    float s = v0 + v1, s2 = v0 * v0 + v1 * v1;
#pragma unroll
    for (int o = 32; o > 0; o >>= 1) {
        s += __shfl_down(s, o); s2 += __shfl_down(s2, o); d += __shfl_down(d, o);
    }
    __shared__ float red[12];
    int w = t >> 6;
    if ((t & 63) == 0) { red[w] = s; red[4 + w] = s2; red[8 + w] = d; }
    __syncthreads();
    s  = red[0] + red[1] + red[2] + red[3];
    s2 = red[4] + red[5] + red[6] + red[7];
    if (t == 0) {
        float dd = red[8] + red[9] + red[10] + red[11];
        dc[row] = 1.f / (1.f + expf(-(dd + b2[0])));
    }
    float mu  = s * (1.f / HDIM);
    float var = fmaf(-mu, mu, s2 * (1.f / HDIM));
    float inv = rsqrtf(var + 1e-5f);
    float n0 = fmaxf(fmaf((v0 - mu) * inv, g[2 * t],     b[2 * t]),     0.f);
    float n1 = fmaxf(fmaf((v1 - mu) * inv, g[2 * t + 1], b[2 * t + 1]), 0.f);
    *(unsigned*)&out[(size_t)row * HDIM + 2 * t] =
        (unsigned)f2bf(n0) | ((unsigned)f2bf(n1) << 16);
}

// ---------------- LayerNorm(512)+ReLU, bf16 in (row stride IS) -> bf16 out [.,512] ----
template<int IS>
__global__ __launch_bounds__(256)
void ln_bf(const ushort* __restrict__ in, ushort* __restrict__ out,
           const float* __restrict__ g, const float* __restrict__ b) {
    int row = blockIdx.x, t = threadIdx.x;
    unsigned u = *(const unsigned*)&in[(size_t)row * IS + 2 * t];
    float v0 = bf2f((ushort)(u & 0xffff)), v1 = bf2f((ushort)(u >> 16));
    float s = v0 + v1, s2 = v0 * v0 + v1 * v1;
#pragma unroll
    for (int o = 32; o > 0; o >>= 1) { s += __shfl_down(s, o); s2 += __shfl_down(s2, o); }
    __shared__ float red[8];
    int w = t >> 6;
    if ((t & 63) == 0) { red[w] = s; red[4 + w] = s2; }
    __syncthreads();
    s  = red[0] + red[1] + red[2] + red[3];
    s2 = red[4] + red[5] + red[6] + red[7];
    float mu  = s * (1.f / HDIM);
    float var = fmaf(-mu, mu, s2 * (1.f / HDIM));
    float inv = rsqrtf(var + 1e-5f);
    float n0 = fmaxf(fmaf((v0 - mu) * inv, g[2 * t],     b[2 * t]),     0.f);
    float n1 = fmaxf(fmaf((v1 - mu) * inv, g[2 * t + 1], b[2 * t + 1]), 0.f);
    *(unsigned*)&out[(size_t)row * HDIM + 2 * t] =
        (unsigned)f2bf(n0) | ((unsigned)f2bf(n1) << 16);
}

extern "C" void kernel_launch(void* const* d_in, const int* in_sizes, int n_in,
                              void* d_out, int out_size, void* d_ws, size_t ws_size,
                              hipStream_t stream) {
    const float* state      = (const float*)d_in[0];
    const float* context    = (const float*)d_in[1];
    const float* edge_attr  = (const float*)d_in[2];
    const int*   edge_index = (const int*)d_in[3];
    const float* ew_w1 = (const float*)d_in[4];
    const float* ew_b1 = (const float*)d_in[5];
    const float* ew_w2 = (const float*)d_in[6];
    const float* ew_b2 = (const float*)d_in[7];
    const float* td_w1 = (const float*)d_in[8];
    const float* td_b1 = (const float*)d_in[9];
    const float* ln1_g = (const float*)d_in[10];
    const float* ln1_b = (const float*)d_in[11];
    const float* td_w2 = (const float*)d_in[12];
    const float* td_b2 = (const float*)d_in[13];
    const float* ln2_g = (const float*)d_in[14];
    const float* ln2_b = (const float*)d_in[15];
    const float* td_w3 = (const float*)d_in[16];
    const float* td_b3 = (const float*)d_in[17];
    const float* df_w1 = (const float*)d_in[18];
    const float* df_b1 = (const float*)d_in[19];
    const float* df_w2 = (const float*)d_in[20];
    const float* df_b2 = (const float*)d_in[21];
    float* out = (float*)d_out;

    float* ws = (float*)d_ws;
    size_t off = 0;
    auto alloc = [&](size_t nfloats) { float* p = ws + off; off += nfloats; return p; };
    float*  ew    = alloc(NEDGE);
    float*  deg   = alloc(N_NODES);
    float*  dis   = alloc(N_NODES);
    float*  ctxp  = alloc((size_t)BATCH * HDIM);
    float*  dc    = alloc(BN_);
    float*  L     = alloc((size_t)N_NODES * N_NODES);                 // 16 MB
    ushort* Lbf   = (ushort*)alloc((size_t)N_NODES * N_NODES / 2);    // 8 MB
    float*  y     = alloc((size_t)BN_ * FDIM);                        // 8 MB
    ushort* yi    = (ushort*)alloc((size_t)BN_ * FDIM / 2);           // 4 MB
    ushort* yiT   = (ushort*)alloc((size_t)BN_ * FDIM / 2);           // 4 MB
    ushort* hcat  = (ushort*)alloc((size_t)BN_ * 768 / 2);            // 12 MB
    ushort* hb1   = (ushort*)alloc((size_t)BN_ * HDIM / 2);           // 8 MB
    ushort* h2b   = (ushort*)alloc((size_t)BN_ * HDIM / 2);           // 8 MB
    ushort* wcat  = (ushort*)alloc((size_t)768 * FDIM / 2);
    ushort* w2T   = (ushort*)alloc((size_t)HDIM * HDIM / 2);
    ushort* w3T   = (ushort*)alloc((size_t)FDIM * HDIM / 2);
    ushort* kb[6];
    for (int s = 0; s < 6; ++s) kb[s] = (ushort*)alloc((size_t)BN_ * FDIM / 2);

    // ---- prep (once per call) ----
    hipMemsetAsync(deg, 0, N_NODES * sizeof(float), stream);
    hipMemsetAsync(L, 0, (size_t)N_NODES * N_NODES * sizeof(float), stream);
    edge_ew_deg<<<NEDGE / 256, 256, 0, stream>>>(edge_attr, edge_index, ew_w1, ew_b1, ew_w2, ew_b2, ew, deg);
    dis_diag<<<N_NODES / 256, 256, 0, stream>>>(deg, dis, L);
    scatter_L<<<NEDGE / 256, 256, 0, stream>>>(edge_index, ew, dis, L);
    cvt_bf16<<<(N_NODES * N_NODES / 4) / 256, 256, 0, stream>>>(L, Lbf);
    ctxproj_kernel<<<BATCH, HDIM, 0, stream>>>(context, td_w1, td_b1, ctxp);
    transpose_cvt<<<dim3(FDIM / 64, HDIM / 64), 256, 0, stream>>>(td_w1, HDIM, wcat, FDIM, HDIM);
    transpose_cvt<<<dim3(FDIM / 64, FDIM / 64), 256, 0, stream>>>(df_w1, FDIM, wcat + (size_t)HDIM * FDIM, FDIM, FDIM);
    transpose_cvt<<<dim3(HDIM / 64, HDIM / 64), 256, 0, stream>>>(td_w2, HDIM, w2T, HDIM, HDIM);
    transpose_cvt<<<dim3(HDIM / 64, FDIM / 64), 256, 0, stream>>>(td_w3, FDIM, w3T, HDIM, FDIM);

    static const double DPA[6][5] = {
        {0, 0, 0, 0, 0},
        {1.0/5, 0, 0, 0, 0},
        {3.0/40, 9.0/40, 0, 0, 0},
        {44.0/45, -56.0/15, 32.0/9, 0, 0},
        {19372.0/6561, -25360.0/2187, 64448.0/6561, -212.0/729, 0},
        {9017.0/3168, -355.0/33, 46732.0/5247, 49.0/176, -5103.0/18656},
    };

    const dim3 cgrid(N_NODES / 64, FDIM / 64, BATCH);
    const float* ycur = state;
    for (int step = 0; step < 4; ++step) {
        for (int s = 0; s < 6; ++s) {
            if (s == 0) {
                if (step == 0)
                    combine_all<<<cgrid, 256, 0, stream>>>(ycur, nullptr, nullptr, nullptr,
                        nullptr, nullptr, 0, 0, 0, 0, 0, nullptr, yi, yiT);
            } else {
                const ushort* p[5] = {nullptr, nullptr, nullptr, nullptr, nullptr};
                float c[5] = {0, 0, 0, 0, 0};
                for (int j = 0; j < s; ++j) { p[j] = kb[j]; c[j] = (float)(DT * DPA[s][j]); }
                combine_all<<<cgrid, 256, 0, stream>>>(ycur, p[0], p[1], p[2], p[3], p[4],
                    c[0], c[1], c[2], c[3], c[4], nullptr, yi, yiT);
            }
            ushort* ks = kb[s];
            // merged G1(+ctx bias) & G4(+df_b1): yi @ wcat^T -> hcat bf16 [8192,768]
            gemm<128, 128, 64, 2, 2, 3, 1><<<dim3(768 / 128, BN_ / 128, 1), 256, 0, stream>>>(
                yi, wcat, ctxp, df_b1, hcat, 768, FDIM, 0, 0, 0);
            ln_dc_768<<<BN_, 256, 0, stream>>>(hcat, hb1, ln1_g, ln1_b, df_w2, df_b2, dc);
            gemm<64, 128, 128, 1, 4, 1, 1><<<dim3(HDIM / 128, BN_ / 64, 1), 256, 0, stream>>>(
                hb1, w2T, td_b2, nullptr, h2b, HDIM, HDIM, 0, 0, 0);
            ln_bf<512><<<BN_, 256, 0, stream>>>(h2b, h2b, ln2_g, ln2_b);
            gemm<64, 64, 128, 2, 2, 1, 1><<<dim3(FDIM / 64, BN_ / 64, 1), 256, 0, stream>>>(
                h2b, w3T, td_b3, nullptr, ks, FDIM, HDIM, 0, 0, 0);
            // merged diffusion over batches: [2048,2048] @ yiT^T -> RMW ks -= dc*Lh
            gemm<64, 64, 128, 2, 2, 0, 2><<<dim3(1024 / 64, N_NODES / 64, 1), 256, 0, stream>>>(
                Lbf, yiT, nullptr, dc, ks, 1024, N_NODES, 0, 0, 0);
        }
        float* dstf = (step == 3) ? out : y;
        combine_all<<<cgrid, 256, 0, stream>>>(ycur,
            kb[0], kb[2], kb[3], kb[4], kb[5],
            (float)(DT * 35.0 / 384), (float)(DT * 500.0 / 1113), (float)(DT * 125.0 / 192),
            (float)(DT * -2187.0 / 6784), (float)(DT * 11.0 / 84),
            dstf, (step == 3) ? nullptr : yi, (step == 3) ? nullptr : yiT);
        ycur = y;
    }
    (void)in_sizes; (void)n_in; (void)out_size; (void)ws_size;
}